// Round 9
// baseline (214.783 us; speedup 1.0000x reference)
//
#include <hip/hip_runtime.h>
#include <hip/hip_bf16.h>

typedef __attribute__((ext_vector_type(8))) short short8v;
typedef __attribute__((ext_vector_type(4))) float float4v;
typedef __attribute__((ext_vector_type(4))) unsigned uint4v;

__device__ __forceinline__ unsigned short f2bf(float x) {
    unsigned u = __float_as_uint(x);
    unsigned r = (u + 0x7fffu + ((u >> 16) & 1u)) >> 16;
    return (unsigned short)r;
}
__device__ __forceinline__ float bf2f(unsigned short u) {
    return __uint_as_float((unsigned)u << 16);
}
__device__ __forceinline__ unsigned cvt_pk_bf16(float lo, float hi) {
    unsigned r;
    asm("v_cvt_pk_bf16_f32 %0, %1, %2" : "=v"(r) : "v"(lo), "v"(hi));
    return r;
}

// ---------- branch 1x1 conv + BN + ReLU (a4: CIN=128, a32: CIN=256) ----------
template<int CIN>
__global__ __launch_bounds__(256) void k_branch(
    const float* __restrict__ x, const float* __restrict__ w,
    const float* __restrict__ s, const float* __restrict__ b,
    float* __restrict__ out, int npix) {
    int t = threadIdx.x;
    int f = t & 31;
    int pi = blockIdx.x * 8 + (t >> 5);
    if (pi >= npix) return;
    const float* xr = x + (size_t)pi * CIN;
    float acc = 0.f;
#pragma unroll 4
    for (int c = 0; c < CIN; ++c) acc = fmaf(xr[c], w[c * 32 + f], acc);
    float v = fmaf(acc, s[f], b[f]);
    out[(size_t)pi * 32 + f] = fmaxf(v, 0.f);
}

// ---------- cat builder: a2 (1x1 conv) + bilinear up of a4, a32 -> bf16 ----------
__global__ __launch_bounds__(256) void k_cat(
    const float* __restrict__ feats2, const float* __restrict__ w2,
    const float* __restrict__ s2, const float* __restrict__ b2,
    const float* __restrict__ a4, const float* __restrict__ a32,
    unsigned short* __restrict__ cat) {
    int t = threadIdx.x;
    int f = t & 31;
    int p = blockIdx.x * 8 + (t >> 5);   // 0..65535
    int y = p >> 8, x = p & 255;

    {
        const float* xr = feats2 + (size_t)p * 64;
        float acc = 0.f;
#pragma unroll 4
        for (int c = 0; c < 64; ++c) acc = fmaf(xr[c], w2[c * 32 + f], acc);
        float v = fmaf(acc, s2[f], b2[f]);
        cat[(size_t)p * 96 + f] = f2bf(fmaxf(v, 0.f));
    }
    {
        float sy = fminf(fmaxf(y * 0.5f - 0.25f, 0.f), 127.f);
        float sx = fminf(fmaxf(x * 0.5f - 0.25f, 0.f), 127.f);
        int y0 = (int)sy; float fy = sy - (float)y0; int y1 = min(y0 + 1, 127);
        int x0 = (int)sx; float fx = sx - (float)x0; int x1 = min(x0 + 1, 127);
        float v00 = a4[((size_t)(y0 * 128 + x0)) * 32 + f];
        float v01 = a4[((size_t)(y0 * 128 + x1)) * 32 + f];
        float v10 = a4[((size_t)(y1 * 128 + x0)) * 32 + f];
        float v11 = a4[((size_t)(y1 * 128 + x1)) * 32 + f];
        float vv = (1.f - fy) * ((1.f - fx) * v00 + fx * v01)
                 + fy * ((1.f - fx) * v10 + fx * v11);
        cat[(size_t)p * 96 + 32 + f] = f2bf(vv);
    }
    {
        float sy = fminf(fmaxf((y + 0.5f) * (1.f / 16.f) - 0.5f, 0.f), 15.f);
        float sx = fminf(fmaxf((x + 0.5f) * (1.f / 16.f) - 0.5f, 0.f), 15.f);
        int y0 = (int)sy; float fy = sy - (float)y0; int y1 = min(y0 + 1, 15);
        int x0 = (int)sx; float fx = sx - (float)x0; int x1 = min(x0 + 1, 15);
        float v00 = a32[((size_t)(y0 * 16 + x0)) * 32 + f];
        float v01 = a32[((size_t)(y0 * 16 + x1)) * 32 + f];
        float v10 = a32[((size_t)(y1 * 16 + x0)) * 32 + f];
        float v11 = a32[((size_t)(y1 * 16 + x1)) * 32 + f];
        float vv = (1.f - fy) * ((1.f - fx) * v00 + fx * v01)
                 + fy * ((1.f - fx) * v10 + fx * v11);
        cat[(size_t)p * 96 + 64 + f] = f2bf(vv);
    }
}

// ---------- pack 3x3 fuse weights to MFMA B-fragment order ----------
__global__ __launch_bounds__(256) void k_packf(
    const float* __restrict__ wf, short* __restrict__ wfp) {
    int i = blockIdx.x * 256 + threadIdx.x;   // 0..82943
    if (i >= 82944) return;
    int j = i & 7;
    int l = (i >> 3) & 63;
    int rest = i >> 9;       // 0..161
    int nt = rest % 6;
    int tk = rest / 6;       // 0..26
    int kt = tk % 3, tap = tk / 3;
    int k = kt * 32 + ((l >> 4) << 3) + j;
    int n = nt * 16 + (l & 15);
    wfp[i] = (short)f2bf(wf[((size_t)(tap * 96 + k)) * 96 + n]);
}

// ---------- pack W1 (4 kt) and W0-feat (3 kt) into B-frag order ----------
__global__ __launch_bounds__(256) void k_pack2(
    const float* __restrict__ w0, const float* __restrict__ w1,
    short* __restrict__ w1p, short* __restrict__ w0fp) {
    int i = blockIdx.x * 256 + threadIdx.x;   // 0..28671
    if (i < 16384) {
        int j = i & 7;
        int l = (i >> 3) & 63;
        int nt = (i >> 9) & 7;
        int kt = i >> 12;
        int k = kt * 32 + ((l >> 4) << 3) + j;
        int n = nt * 16 + (l & 15);
        w1p[i] = (short)f2bf(w1[k * 128 + n]);
    } else {
        int i2 = i - 16384;                   // 0..12287
        int j = i2 & 7;
        int l = (i2 >> 3) & 63;
        int nt = (i2 >> 9) & 7;
        int kt = i2 >> 12;                    // 0..2
        int k = kt * 32 + ((l >> 4) << 3) + j;   // 0..95
        int n = nt * 16 + (l & 15);
        w0fp[i2] = (short)f2bf(w0[k * 128 + n]);
    }
}

// ---------- corr[case][d] = ry*W0y[d] + rx*W0x[d] + b0[d], case=(ry2+1)*4+(rx2+1) ----------
__global__ __launch_bounds__(256) void k_corr(
    const float* __restrict__ w0, const float* __restrict__ b0,
    float* __restrict__ corr) {
    int i = blockIdx.x * 256 + threadIdx.x;   // 0..2047
    int d = i & 127, c = i >> 7;
    float ry = (float)(c >> 2) - 1.5f;
    float rx = (float)(c & 3) - 1.5f;
    corr[i] = fmaf(ry, w0[96 * 128 + d], fmaf(rx, w0[97 * 128 + d], b0[d]));
}

// ---------- 3x3 conv (MFMA) + BN + ReLU -> feat (LDS) -> G = feat @ W0f ----------
__global__ __launch_bounds__(256, 4) void k_fuseG(
    const unsigned short* __restrict__ catb, const short* __restrict__ wfp,
    const float* __restrict__ sf, const float* __restrict__ bfb,
    const short* __restrict__ w0fp, unsigned short* __restrict__ G) {
    __shared__ char Xb[100 * 256];
    int t = threadIdx.x;
    int by = (blockIdx.x >> 5) * 8;
    int bx = (blockIdx.x & 31) * 8;

    if (t < 200) {
        int rp = t >> 1, hf = t & 1;
        int gy = by + rp / 10 - 1;
        int gx = bx + rp % 10 - 1;
        bool ok = (gy >= 0 && gy < 256 && gx >= 0 && gx < 256);
        const unsigned short* src = catb + (size_t)(gy * 256 + gx) * 96 + hf * 48;
        int swz = (rp & 7) << 4;
#pragma unroll
        for (int m = 0; m < 6; ++m) {
            short8v v = {0, 0, 0, 0, 0, 0, 0, 0};
            if (ok) v = *(const short8v*)(src + m * 8);
            *(short8v*)(Xb + rp * 256 + (((hf * 6 + m) * 16) ^ swz)) = v;
        }
    }
    __syncthreads();

    int lane = t & 63, wid = t >> 6;
    int wr = wid >> 1, wc = wid & 1;
    int l15 = lane & 15, g = lane >> 4, kb = g * 16;

    float4v acc[2][3];
#pragma unroll
    for (int rb = 0; rb < 2; ++rb)
#pragma unroll
        for (int n = 0; n < 3; ++n)
            acc[rb][n] = (float4v){0.f, 0.f, 0.f, 0.f};

#pragma unroll
    for (int ky = 0; ky < 3; ++ky) {
#pragma unroll
        for (int kx = 0; kx < 3; ++kx) {
#pragma unroll
            for (int kt = 0; kt < 3; ++kt) {
                const short8v* bp = (const short8v*)wfp
                    + (size_t)((((ky * 3 + kx) * 3 + kt) * 6) + wc * 3) * 64 + lane;
                short8v b0 = bp[0], b1 = bp[64], b2 = bp[128];
#pragma unroll
                for (int rb = 0; rb < 2; ++rb) {
                    int R = wr * 32 + rb * 16 + l15;
                    int rp = ((R >> 3) + ky) * 10 + (R & 7) + kx;
                    short8v a = *(short8v*)(Xb + rp * 256
                                 + ((kt * 64 + kb) ^ ((rp & 7) << 4)));
                    acc[rb][0] = __builtin_amdgcn_mfma_f32_16x16x32_bf16(a, b0, acc[rb][0], 0, 0, 0);
                    acc[rb][1] = __builtin_amdgcn_mfma_f32_16x16x32_bf16(a, b1, acc[rb][1], 0, 0, 0);
                    acc[rb][2] = __builtin_amdgcn_mfma_f32_16x16x32_bf16(a, b2, acc[rb][2], 0, 0, 0);
                }
            }
        }
    }
    __syncthreads();   // conv LDS reads done; Xb reusable

    // feat (bf16, BN+ReLU applied) -> Xb as [64 rows][96 ch], pitch 256, swizzled
#pragma unroll
    for (int rb = 0; rb < 2; ++rb) {
#pragma unroll
        for (int n = 0; n < 3; ++n) {
            int ch = (wc * 3 + n) * 16 + l15;
            float sc = sf[ch], bi = bfb[ch];
#pragma unroll
            for (int j = 0; j < 4; ++j) {
                int R = wr * 32 + rb * 16 + g * 4 + j;
                *(short*)(Xb + R * 256 + ((ch * 2) ^ ((R & 7) << 4))) =
                    (short)f2bf(fmaxf(fmaf(acc[rb][n][j], sc, bi), 0.f));
            }
        }
    }
    __syncthreads();

    // G-stage: 64 rows x 128 cols, K=96. Wave wid owns cols [32*wid, 32*wid+32).
    float4v a2[4][2];
#pragma unroll
    for (int r = 0; r < 4; ++r)
#pragma unroll
        for (int n = 0; n < 2; ++n)
            a2[r][n] = (float4v){0.f, 0.f, 0.f, 0.f};

#pragma unroll
    for (int kt = 0; kt < 3; ++kt) {
        const short8v* bp = (const short8v*)w0fp + (kt * 8 + wid * 2) * 64 + lane;
        short8v b0 = bp[0], b1 = bp[64];
#pragma unroll
        for (int r = 0; r < 4; ++r) {
            int row = r * 16 + l15;
            short8v a = *(short8v*)(Xb + row * 256 + ((kt * 64 + kb) ^ ((row & 7) << 4)));
            a2[r][0] = __builtin_amdgcn_mfma_f32_16x16x32_bf16(a, b0, a2[r][0], 0, 0, 0);
            a2[r][1] = __builtin_amdgcn_mfma_f32_16x16x32_bf16(a, b1, a2[r][1], 0, 0, 0);
        }
    }

#pragma unroll
    for (int r = 0; r < 4; ++r) {
#pragma unroll
        for (int n = 0; n < 2; ++n) {
            int colg = (wid * 2 + n) * 16 + l15;
#pragma unroll
            for (int j = 0; j < 4; ++j) {
                int R = r * 16 + g * 4 + j;
                int pix = (by + (R >> 3)) * 256 + bx + (R & 7);
                G[(size_t)pix * 128 + colg] = f2bf(a2[r][n][j]);
            }
        }
    }
}

// ---------- persistent-block fused LIIF query ----------
// 1024 blocks (XCD-chunked), 4 waves; each block loops 8 subtiles of 32 px.
// W1 in LDS (staged once). No barriers in loop: each wave owns 8 px/subtile
// end-to-end (gather -> build -> MFMA -> reduce -> ensemble in-lane).
// G double-buffered in registers (prefetch s+1 before compute of s).
#define GATHER8(sbase, gvv, cse)                                              \
    {                                                                         \
        _Pragma("unroll")                                                     \
        for (int rt = 0; rt < 2; ++rt) {                                      \
            int row = wid * 32 + rt * 16 + l15;                               \
            int p = (sbase) + (row >> 2);                                     \
            int br = row & 3;                                                 \
            int qy = p >> 9, qx = p & 511;                                    \
            int iy = min(max((qy + ((br & 2) ? 1 : -1)) >> 1, 0), 255);       \
            int ix = min(max((qx + ((br & 1) ? 1 : -1)) >> 1, 0), 255);       \
            cse[rt] = (qy - 2 * iy + 1) * 4 + (qx - 2 * ix + 1);              \
            const unsigned short* gp = G + ((size_t)(iy * 256 + ix)) * 128 + g * 8; \
            _Pragma("unroll")                                                 \
            for (int kt = 0; kt < 4; ++kt)                                    \
                gvv[rt][kt] = *(const short8v*)(gp + kt * 32);                \
        }                                                                     \
    }

__global__ __launch_bounds__(256) void k_mlp8(
    const unsigned short* __restrict__ G,
    const float* __restrict__ corr,
    const short* __restrict__ w1p, const float* __restrict__ b1g,
    const float* __restrict__ w2g, const float* __restrict__ b2g,
    float* __restrict__ out) {
    __shared__ short8v Bs[2048];       // 32KB packed W1
    int t = threadIdx.x;
    int lane = t & 63, wid = t >> 6;
    int l15 = lane & 15, g = lane >> 4;

    // stage W1 into LDS (coalesced, once per block)
    {
        const short8v* wp = (const short8v*)w1p;
#pragma unroll
        for (int i = 0; i < 8; ++i)
            Bs[t + i * 256] = wp[t + i * 256];
    }

    float b1v[8], w2v[8];
#pragma unroll
    for (int nt = 0; nt < 8; ++nt) {
        b1v[nt] = b1g[nt * 16 + l15];
        w2v[nt] = w2g[nt * 16 + l15];
    }
    float bb = b2g[0];

    // XCD-chunked mapping: 8 XCDs x 128 blocks x 8 subtiles x 32 px
    int base0 = (blockIdx.x & 7) * 32768 + (blockIdx.x >> 3) * 256;

    short8v gbuf[2][2][4];
    int cbuf[2][2];
    GATHER8(base0, gbuf[0], cbuf[0]);
    __syncthreads();   // Bs staged

#pragma unroll
    for (int s = 0; s < 8; ++s) {
        const int cur = s & 1, nxt = cur ^ 1;
        int sbase = base0 + s * 32;
        if (s < 7) GATHER8(sbase + 32, gbuf[nxt], cbuf[nxt]);

        // build A-frags: H = relu(G + corr[case]), packed bf16
        short8v afrag[2][4];
#pragma unroll
        for (int rt = 0; rt < 2; ++rt) {
            const float* cp = corr + cbuf[cur][rt] * 128 + g * 8;
#pragma unroll
            for (int kt = 0; kt < 4; ++kt) {
                short8v gv = gbuf[cur][rt][kt];
                float4 c0 = *(const float4*)(cp + kt * 32);
                float4 c1 = *(const float4*)(cp + kt * 32 + 4);
                uint4v u;
                u[0] = cvt_pk_bf16(fmaxf(bf2f((unsigned short)gv[0]) + c0.x, 0.f),
                                   fmaxf(bf2f((unsigned short)gv[1]) + c0.y, 0.f));
                u[1] = cvt_pk_bf16(fmaxf(bf2f((unsigned short)gv[2]) + c0.z, 0.f),
                                   fmaxf(bf2f((unsigned short)gv[3]) + c0.w, 0.f));
                u[2] = cvt_pk_bf16(fmaxf(bf2f((unsigned short)gv[4]) + c1.x, 0.f),
                                   fmaxf(bf2f((unsigned short)gv[5]) + c1.y, 0.f));
                u[3] = cvt_pk_bf16(fmaxf(bf2f((unsigned short)gv[6]) + c1.z, 0.f),
                                   fmaxf(bf2f((unsigned short)gv[7]) + c1.w, 0.f));
                afrag[rt][kt] = __builtin_bit_cast(short8v, u);
            }
        }

        // layer 1 MFMA (nt-halves to keep acc at 32 VGPR) + fused layer 2
        float part[2][4];
#pragma unroll
        for (int rt = 0; rt < 2; ++rt)
#pragma unroll
            for (int j = 0; j < 4; ++j) part[rt][j] = 0.f;

#pragma unroll
        for (int nh = 0; nh < 2; ++nh) {
            float4v acc[2][4];
#pragma unroll
            for (int rt = 0; rt < 2; ++rt)
#pragma unroll
                for (int n = 0; n < 4; ++n)
                    acc[rt][n] = (float4v){0.f, 0.f, 0.f, 0.f};
#pragma unroll
            for (int kt = 0; kt < 4; ++kt) {
#pragma unroll
                for (int n = 0; n < 4; ++n) {
                    short8v b = Bs[(kt * 8 + nh * 4 + n) * 64 + lane];
                    acc[0][n] = __builtin_amdgcn_mfma_f32_16x16x32_bf16(afrag[0][kt], b, acc[0][n], 0, 0, 0);
                    acc[1][n] = __builtin_amdgcn_mfma_f32_16x16x32_bf16(afrag[1][kt], b, acc[1][n], 0, 0, 0);
                }
            }
#pragma unroll
            for (int rt = 0; rt < 2; ++rt)
#pragma unroll
                for (int n = 0; n < 4; ++n)
#pragma unroll
                    for (int j = 0; j < 4; ++j)
                        part[rt][j] += fmaxf(acc[rt][n][j] + b1v[nh * 4 + n], 0.f)
                                     * w2v[nh * 4 + n];
        }

        // 16-lane reduce: lane (g, l15==0) then holds pixel (wid*8+rt*4+g)'s quad
#pragma unroll
        for (int off = 8; off >= 1; off >>= 1)
#pragma unroll
            for (int rt = 0; rt < 2; ++rt)
#pragma unroll
                for (int j = 0; j < 4; ++j)
                    part[rt][j] += __shfl_xor(part[rt][j], off);

        if (l15 == 0) {
#pragma unroll
            for (int rt = 0; rt < 2; ++rt) {
                int p = sbase + wid * 8 + rt * 4 + g;
                int qy = p >> 9, qx = p & 511;
                float ar[4];
#pragma unroll
                for (int br = 0; br < 4; ++br) {
                    int iy = min(max((qy + ((br & 2) ? 1 : -1)) >> 1, 0), 255);
                    int ix = min(max((qx + ((br & 1) ? 1 : -1)) >> 1, 0), 255);
                    float ry = (float)(qy - 2 * iy) - 0.5f;
                    float rx = (float)(qx - 2 * ix) - 0.5f;
                    ar[br] = fabsf(ry * rx) + 1e-9f;
                }
                out[p] = ((part[rt][0] + bb) * ar[3] + (part[rt][1] + bb) * ar[2]
                        + (part[rt][2] + bb) * ar[1] + (part[rt][3] + bb) * ar[0])
                       / (ar[0] + ar[1] + ar[2] + ar[3]);
            }
        }
    }
}

// ---------- host launcher ----------
extern "C" void kernel_launch(void* const* d_in, const int* in_sizes, int n_in,
                              void* d_out, int out_size, void* d_ws, size_t ws_size,
                              hipStream_t stream) {
    const float* feats2 = (const float*)d_in[0];
    const float* feats4 = (const float*)d_in[1];
    const float* feats32 = (const float*)d_in[2];
    const float* w2 = (const float*)d_in[4];
    const float* s2 = (const float*)d_in[5];
    const float* b2 = (const float*)d_in[6];
    const float* w4 = (const float*)d_in[7];
    const float* s4 = (const float*)d_in[8];
    const float* b4 = (const float*)d_in[9];
    const float* w32 = (const float*)d_in[10];
    const float* s32 = (const float*)d_in[11];
    const float* b32 = (const float*)d_in[12];
    const float* wf = (const float*)d_in[13];
    const float* sf = (const float*)d_in[14];
    const float* bf = (const float*)d_in[15];
    const float* mw0 = (const float*)d_in[16];
    const float* mb0 = (const float*)d_in[17];
    const float* mw1 = (const float*)d_in[18];
    const float* mb1 = (const float*)d_in[19];
    const float* mw2 = (const float*)d_in[20];
    const float* mb2 = (const float*)d_in[21];

    float* a4buf = (float*)d_ws;                          // 128*128*32 f32
    float* a32buf = a4buf + 524288;                       // 16*16*32 f32
    unsigned short* catb16 = (unsigned short*)(a32buf + 8192);   // 65536*96 bf16
    unsigned short* Gbuf = catb16 + 6291456;                     // 65536*128 bf16
    short* w1p = (short*)(Gbuf + 8388608);                // 16384 bf16
    short* w0fp = w1p + 16384;                            // 12288 bf16
    short* wfp = w0fp + 12288;                            // 82944 bf16
    float* corrbuf = (float*)(wfp + 82944);               // 16*128 f32

    k_pack2<<<112, 256, 0, stream>>>(mw0, mw1, w1p, w0fp);
    k_packf<<<324, 256, 0, stream>>>(wf, wfp);
    k_corr<<<8, 256, 0, stream>>>(mw0, mb0, corrbuf);
    k_branch<128><<<2048, 256, 0, stream>>>(feats4, w4, s4, b4, a4buf, 16384);
    k_branch<256><<<32, 256, 0, stream>>>(feats32, w32, s32, b32, a32buf, 256);
    k_cat<<<8192, 256, 0, stream>>>(feats2, w2, s2, b2, a4buf, a32buf, catb16);
    k_fuseG<<<1024, 256, 0, stream>>>(catb16, wfp, sf, bf, w0fp, Gbuf);
    k_mlp8<<<1024, 256, 0, stream>>>(Gbuf, corrbuf, w1p, mb1, mw2, mb2,
                                     (float*)d_out);
}

// Round 10
// 202.052 us; speedup vs baseline: 1.0630x; 1.0630x over previous
//
#include <hip/hip_runtime.h>
#include <hip/hip_bf16.h>

typedef __attribute__((ext_vector_type(8))) short short8v;
typedef __attribute__((ext_vector_type(4))) float float4v;
typedef __attribute__((ext_vector_type(4))) unsigned uint4v;

__device__ __forceinline__ unsigned short f2bf(float x) {
    unsigned u = __float_as_uint(x);
    unsigned r = (u + 0x7fffu + ((u >> 16) & 1u)) >> 16;
    return (unsigned short)r;
}
__device__ __forceinline__ float bf2f(unsigned short u) {
    return __uint_as_float((unsigned)u << 16);
}
__device__ __forceinline__ unsigned cvt_pk_bf16(float lo, float hi) {
    unsigned r;
    asm("v_cvt_pk_bf16_f32 %0, %1, %2" : "=v"(r) : "v"(lo), "v"(hi));
    return r;
}
// sum across each 16-lane row (fixed lane>>4 group), result in all lanes.
// VALU-pipe only (DPP), no LDS traffic: quad_perm swaps 1,2 + row_ror 4,8.
__device__ __forceinline__ float dpp_red16(float v) {
    int x = __float_as_int(v);
    v += __int_as_float(__builtin_amdgcn_update_dpp(0, x, 0xB1, 0xF, 0xF, false));
    x = __float_as_int(v);
    v += __int_as_float(__builtin_amdgcn_update_dpp(0, x, 0x4E, 0xF, 0xF, false));
    x = __float_as_int(v);
    v += __int_as_float(__builtin_amdgcn_update_dpp(0, x, 0x124, 0xF, 0xF, false));
    x = __float_as_int(v);
    v += __int_as_float(__builtin_amdgcn_update_dpp(0, x, 0x128, 0xF, 0xF, false));
    return v;
}

// ---------- branch 1x1 conv + BN + ReLU (a4: CIN=128, a32: CIN=256) ----------
template<int CIN>
__global__ __launch_bounds__(256) void k_branch(
    const float* __restrict__ x, const float* __restrict__ w,
    const float* __restrict__ s, const float* __restrict__ b,
    float* __restrict__ out, int npix) {
    int t = threadIdx.x;
    int f = t & 31;
    int pi = blockIdx.x * 8 + (t >> 5);
    if (pi >= npix) return;
    const float* xr = x + (size_t)pi * CIN;
    float acc = 0.f;
#pragma unroll 4
    for (int c = 0; c < CIN; ++c) acc = fmaf(xr[c], w[c * 32 + f], acc);
    float v = fmaf(acc, s[f], b[f]);
    out[(size_t)pi * 32 + f] = fmaxf(v, 0.f);
}

// ---------- cat builder: a2 (1x1 conv) + bilinear up of a4, a32 -> bf16 ----------
__global__ __launch_bounds__(256) void k_cat(
    const float* __restrict__ feats2, const float* __restrict__ w2,
    const float* __restrict__ s2, const float* __restrict__ b2,
    const float* __restrict__ a4, const float* __restrict__ a32,
    unsigned short* __restrict__ cat) {
    int t = threadIdx.x;
    int f = t & 31;
    int p = blockIdx.x * 8 + (t >> 5);   // 0..65535
    int y = p >> 8, x = p & 255;

    {
        const float* xr = feats2 + (size_t)p * 64;
        float acc = 0.f;
#pragma unroll 4
        for (int c = 0; c < 64; ++c) acc = fmaf(xr[c], w2[c * 32 + f], acc);
        float v = fmaf(acc, s2[f], b2[f]);
        cat[(size_t)p * 96 + f] = f2bf(fmaxf(v, 0.f));
    }
    {
        float sy = fminf(fmaxf(y * 0.5f - 0.25f, 0.f), 127.f);
        float sx = fminf(fmaxf(x * 0.5f - 0.25f, 0.f), 127.f);
        int y0 = (int)sy; float fy = sy - (float)y0; int y1 = min(y0 + 1, 127);
        int x0 = (int)sx; float fx = sx - (float)x0; int x1 = min(x0 + 1, 127);
        float v00 = a4[((size_t)(y0 * 128 + x0)) * 32 + f];
        float v01 = a4[((size_t)(y0 * 128 + x1)) * 32 + f];
        float v10 = a4[((size_t)(y1 * 128 + x0)) * 32 + f];
        float v11 = a4[((size_t)(y1 * 128 + x1)) * 32 + f];
        float vv = (1.f - fy) * ((1.f - fx) * v00 + fx * v01)
                 + fy * ((1.f - fx) * v10 + fx * v11);
        cat[(size_t)p * 96 + 32 + f] = f2bf(vv);
    }
    {
        float sy = fminf(fmaxf((y + 0.5f) * (1.f / 16.f) - 0.5f, 0.f), 15.f);
        float sx = fminf(fmaxf((x + 0.5f) * (1.f / 16.f) - 0.5f, 0.f), 15.f);
        int y0 = (int)sy; float fy = sy - (float)y0; int y1 = min(y0 + 1, 15);
        int x0 = (int)sx; float fx = sx - (float)x0; int x1 = min(x0 + 1, 15);
        float v00 = a32[((size_t)(y0 * 16 + x0)) * 32 + f];
        float v01 = a32[((size_t)(y0 * 16 + x1)) * 32 + f];
        float v10 = a32[((size_t)(y1 * 16 + x0)) * 32 + f];
        float v11 = a32[((size_t)(y1 * 16 + x1)) * 32 + f];
        float vv = (1.f - fy) * ((1.f - fx) * v00 + fx * v01)
                 + fy * ((1.f - fx) * v10 + fx * v11);
        cat[(size_t)p * 96 + 64 + f] = f2bf(vv);
    }
}

// ---------- pack 3x3 fuse weights to MFMA B-fragment order ----------
__global__ __launch_bounds__(256) void k_packf(
    const float* __restrict__ wf, short* __restrict__ wfp) {
    int i = blockIdx.x * 256 + threadIdx.x;   // 0..82943
    if (i >= 82944) return;
    int j = i & 7;
    int l = (i >> 3) & 63;
    int rest = i >> 9;       // 0..161
    int nt = rest % 6;
    int tk = rest / 6;       // 0..26
    int kt = tk % 3, tap = tk / 3;
    int k = kt * 32 + ((l >> 4) << 3) + j;
    int n = nt * 16 + (l & 15);
    wfp[i] = (short)f2bf(wf[((size_t)(tap * 96 + k)) * 96 + n]);
}

// ---------- pack W1 (4 kt) and W0-feat (3 kt) into B-frag order ----------
__global__ __launch_bounds__(256) void k_pack2(
    const float* __restrict__ w0, const float* __restrict__ w1,
    short* __restrict__ w1p, short* __restrict__ w0fp) {
    int i = blockIdx.x * 256 + threadIdx.x;   // 0..28671
    if (i < 16384) {
        int j = i & 7;
        int l = (i >> 3) & 63;
        int nt = (i >> 9) & 7;
        int kt = i >> 12;
        int k = kt * 32 + ((l >> 4) << 3) + j;
        int n = nt * 16 + (l & 15);
        w1p[i] = (short)f2bf(w1[k * 128 + n]);
    } else {
        int i2 = i - 16384;                   // 0..12287
        int j = i2 & 7;
        int l = (i2 >> 3) & 63;
        int nt = (i2 >> 9) & 7;
        int kt = i2 >> 12;                    // 0..2
        int k = kt * 32 + ((l >> 4) << 3) + j;   // 0..95
        int n = nt * 16 + (l & 15);
        w0fp[i2] = (short)f2bf(w0[k * 128 + n]);
    }
}

// ---------- corr[case][d] = ry*W0y[d] + rx*W0x[d] + b0[d], case=(ry2+1)*4+(rx2+1) ----------
__global__ __launch_bounds__(256) void k_corr(
    const float* __restrict__ w0, const float* __restrict__ b0,
    float* __restrict__ corr) {
    int i = blockIdx.x * 256 + threadIdx.x;   // 0..2047
    int d = i & 127, c = i >> 7;
    float ry = (float)(c >> 2) - 1.5f;
    float rx = (float)(c & 3) - 1.5f;
    corr[i] = fmaf(ry, w0[96 * 128 + d], fmaf(rx, w0[97 * 128 + d], b0[d]));
}

// ---------- 3x3 conv (MFMA) + BN + ReLU -> feat (LDS) -> G = feat @ W0f ----------
__global__ __launch_bounds__(256, 4) void k_fuseG(
    const unsigned short* __restrict__ catb, const short* __restrict__ wfp,
    const float* __restrict__ sf, const float* __restrict__ bfb,
    const short* __restrict__ w0fp, unsigned short* __restrict__ G) {
    __shared__ char Xb[100 * 256];
    int t = threadIdx.x;
    int by = (blockIdx.x >> 5) * 8;
    int bx = (blockIdx.x & 31) * 8;

    if (t < 200) {
        int rp = t >> 1, hf = t & 1;
        int gy = by + rp / 10 - 1;
        int gx = bx + rp % 10 - 1;
        bool ok = (gy >= 0 && gy < 256 && gx >= 0 && gx < 256);
        const unsigned short* src = catb + (size_t)(gy * 256 + gx) * 96 + hf * 48;
        int swz = (rp & 7) << 4;
#pragma unroll
        for (int m = 0; m < 6; ++m) {
            short8v v = {0, 0, 0, 0, 0, 0, 0, 0};
            if (ok) v = *(const short8v*)(src + m * 8);
            *(short8v*)(Xb + rp * 256 + (((hf * 6 + m) * 16) ^ swz)) = v;
        }
    }
    __syncthreads();

    int lane = t & 63, wid = t >> 6;
    int wr = wid >> 1, wc = wid & 1;
    int l15 = lane & 15, g = lane >> 4, kb = g * 16;

    float4v acc[2][3];
#pragma unroll
    for (int rb = 0; rb < 2; ++rb)
#pragma unroll
        for (int n = 0; n < 3; ++n)
            acc[rb][n] = (float4v){0.f, 0.f, 0.f, 0.f};

#pragma unroll
    for (int ky = 0; ky < 3; ++ky) {
#pragma unroll
        for (int kx = 0; kx < 3; ++kx) {
#pragma unroll
            for (int kt = 0; kt < 3; ++kt) {
                const short8v* bp = (const short8v*)wfp
                    + (size_t)((((ky * 3 + kx) * 3 + kt) * 6) + wc * 3) * 64 + lane;
                short8v b0 = bp[0], b1 = bp[64], b2 = bp[128];
#pragma unroll
                for (int rb = 0; rb < 2; ++rb) {
                    int R = wr * 32 + rb * 16 + l15;
                    int rp = ((R >> 3) + ky) * 10 + (R & 7) + kx;
                    short8v a = *(short8v*)(Xb + rp * 256
                                 + ((kt * 64 + kb) ^ ((rp & 7) << 4)));
                    acc[rb][0] = __builtin_amdgcn_mfma_f32_16x16x32_bf16(a, b0, acc[rb][0], 0, 0, 0);
                    acc[rb][1] = __builtin_amdgcn_mfma_f32_16x16x32_bf16(a, b1, acc[rb][1], 0, 0, 0);
                    acc[rb][2] = __builtin_amdgcn_mfma_f32_16x16x32_bf16(a, b2, acc[rb][2], 0, 0, 0);
                }
            }
        }
    }
    __syncthreads();   // conv LDS reads done; Xb reusable

    // feat (bf16, BN+ReLU applied) -> Xb as [64 rows][96 ch], pitch 256, swizzled
#pragma unroll
    for (int rb = 0; rb < 2; ++rb) {
#pragma unroll
        for (int n = 0; n < 3; ++n) {
            int ch = (wc * 3 + n) * 16 + l15;
            float sc = sf[ch], bi = bfb[ch];
#pragma unroll
            for (int j = 0; j < 4; ++j) {
                int R = wr * 32 + rb * 16 + g * 4 + j;
                *(short*)(Xb + R * 256 + ((ch * 2) ^ ((R & 7) << 4))) =
                    (short)f2bf(fmaxf(fmaf(acc[rb][n][j], sc, bi), 0.f));
            }
        }
    }
    __syncthreads();

    // G-stage: 64 rows x 128 cols, K=96. Wave wid owns cols [32*wid, 32*wid+32).
    float4v a2[4][2];
#pragma unroll
    for (int r = 0; r < 4; ++r)
#pragma unroll
        for (int n = 0; n < 2; ++n)
            a2[r][n] = (float4v){0.f, 0.f, 0.f, 0.f};

#pragma unroll
    for (int kt = 0; kt < 3; ++kt) {
        const short8v* bp = (const short8v*)w0fp + (kt * 8 + wid * 2) * 64 + lane;
        short8v b0 = bp[0], b1 = bp[64];
#pragma unroll
        for (int r = 0; r < 4; ++r) {
            int row = r * 16 + l15;
            short8v a = *(short8v*)(Xb + row * 256 + ((kt * 64 + kb) ^ ((row & 7) << 4)));
            a2[r][0] = __builtin_amdgcn_mfma_f32_16x16x32_bf16(a, b0, a2[r][0], 0, 0, 0);
            a2[r][1] = __builtin_amdgcn_mfma_f32_16x16x32_bf16(a, b1, a2[r][1], 0, 0, 0);
        }
    }

#pragma unroll
    for (int r = 0; r < 4; ++r) {
#pragma unroll
        for (int n = 0; n < 2; ++n) {
            int colg = (wid * 2 + n) * 16 + l15;
#pragma unroll
            for (int j = 0; j < 4; ++j) {
                int R = r * 16 + g * 4 + j;
                int pix = (by + (R >> 3)) * 256 + bx + (R & 7);
                G[(size_t)pix * 128 + colg] = f2bf(a2[r][n][j]);
            }
        }
    }
}

// ---------- persistent-block fused LIIF query (barrier-free loop) ----------
// 2048 blocks (XCD-chunked), 4 waves; each block loops 4 subtiles of 32 px.
// W1 in LDS (staged once). DPP tree-reduce (VALU pipe, no LDS). All-lane
// epilogue, masked store. G double-buffered in registers.
#define GATHER8(sbase, gvv, cse)                                              \
    {                                                                         \
        _Pragma("unroll")                                                     \
        for (int rt = 0; rt < 2; ++rt) {                                      \
            int row = wid * 32 + rt * 16 + l15;                               \
            int p = (sbase) + (row >> 2);                                     \
            int br = row & 3;                                                 \
            int qy = p >> 9, qx = p & 511;                                    \
            int iy = min(max((qy + ((br & 2) ? 1 : -1)) >> 1, 0), 255);       \
            int ix = min(max((qx + ((br & 1) ? 1 : -1)) >> 1, 0), 255);       \
            cse[rt] = (qy - 2 * iy + 1) * 4 + (qx - 2 * ix + 1);              \
            const unsigned short* gp = G + ((size_t)(iy * 256 + ix)) * 128 + g * 8; \
            _Pragma("unroll")                                                 \
            for (int kt = 0; kt < 4; ++kt)                                    \
                gvv[rt][kt] = *(const short8v*)(gp + kt * 32);                \
        }                                                                     \
    }

__global__ __launch_bounds__(256) void k_mlp9(
    const unsigned short* __restrict__ G,
    const float* __restrict__ corr,
    const short* __restrict__ w1p, const float* __restrict__ b1g,
    const float* __restrict__ w2g, const float* __restrict__ b2g,
    float* __restrict__ out) {
    __shared__ short8v Bs[2048];       // 32KB packed W1
    int t = threadIdx.x;
    int lane = t & 63, wid = t >> 6;
    int l15 = lane & 15, g = lane >> 4;

    // stage W1 into LDS (coalesced, once per block)
    {
        const short8v* wp = (const short8v*)w1p;
#pragma unroll
        for (int i = 0; i < 8; ++i)
            Bs[t + i * 256] = wp[t + i * 256];
    }

    float b1v[8], w2v[8];
#pragma unroll
    for (int nt = 0; nt < 8; ++nt) {
        b1v[nt] = b1g[nt * 16 + l15];
        w2v[nt] = w2g[nt * 16 + l15];
    }
    float bb = b2g[0];

    // XCD-chunked mapping: 8 XCDs x 256 blocks x 4 subtiles x 32 px
    int base0 = (blockIdx.x & 7) * 32768 + (blockIdx.x >> 3) * 128;

    short8v gbuf[2][2][4];
    int cbuf[2][2];
    GATHER8(base0, gbuf[0], cbuf[0]);
    __syncthreads();   // Bs staged

#pragma unroll
    for (int s = 0; s < 4; ++s) {
        const int cur = s & 1, nxt = cur ^ 1;
        int sbase = base0 + s * 32;
        if (s < 3) GATHER8(sbase + 32, gbuf[nxt], cbuf[nxt]);

        // build A-frags: H = relu(G + corr[case]), packed bf16
        short8v afrag[2][4];
#pragma unroll
        for (int rt = 0; rt < 2; ++rt) {
            const float* cp = corr + cbuf[cur][rt] * 128 + g * 8;
#pragma unroll
            for (int kt = 0; kt < 4; ++kt) {
                short8v gv = gbuf[cur][rt][kt];
                float4 c0 = *(const float4*)(cp + kt * 32);
                float4 c1 = *(const float4*)(cp + kt * 32 + 4);
                uint4v u;
                u[0] = cvt_pk_bf16(fmaxf(bf2f((unsigned short)gv[0]) + c0.x, 0.f),
                                   fmaxf(bf2f((unsigned short)gv[1]) + c0.y, 0.f));
                u[1] = cvt_pk_bf16(fmaxf(bf2f((unsigned short)gv[2]) + c0.z, 0.f),
                                   fmaxf(bf2f((unsigned short)gv[3]) + c0.w, 0.f));
                u[2] = cvt_pk_bf16(fmaxf(bf2f((unsigned short)gv[4]) + c1.x, 0.f),
                                   fmaxf(bf2f((unsigned short)gv[5]) + c1.y, 0.f));
                u[3] = cvt_pk_bf16(fmaxf(bf2f((unsigned short)gv[6]) + c1.z, 0.f),
                                   fmaxf(bf2f((unsigned short)gv[7]) + c1.w, 0.f));
                afrag[rt][kt] = __builtin_bit_cast(short8v, u);
            }
        }

        // layer 1 MFMA (nt-halves to keep acc at 32 VGPR) + fused layer 2
        float part[2][4];
#pragma unroll
        for (int rt = 0; rt < 2; ++rt)
#pragma unroll
            for (int j = 0; j < 4; ++j) part[rt][j] = 0.f;

#pragma unroll
        for (int nh = 0; nh < 2; ++nh) {
            float4v acc[2][4];
#pragma unroll
            for (int rt = 0; rt < 2; ++rt)
#pragma unroll
                for (int n = 0; n < 4; ++n)
                    acc[rt][n] = (float4v){0.f, 0.f, 0.f, 0.f};
            __builtin_amdgcn_s_setprio(1);
#pragma unroll
            for (int kt = 0; kt < 4; ++kt) {
#pragma unroll
                for (int n = 0; n < 4; ++n) {
                    short8v b = Bs[(kt * 8 + nh * 4 + n) * 64 + lane];
                    acc[0][n] = __builtin_amdgcn_mfma_f32_16x16x32_bf16(afrag[0][kt], b, acc[0][n], 0, 0, 0);
                    acc[1][n] = __builtin_amdgcn_mfma_f32_16x16x32_bf16(afrag[1][kt], b, acc[1][n], 0, 0, 0);
                }
            }
            __builtin_amdgcn_s_setprio(0);
#pragma unroll
            for (int rt = 0; rt < 2; ++rt)
#pragma unroll
                for (int n = 0; n < 4; ++n)
#pragma unroll
                    for (int j = 0; j < 4; ++j)
                        part[rt][j] += fmaxf(acc[rt][n][j] + b1v[nh * 4 + n], 0.f)
                                     * w2v[nh * 4 + n];
        }

        // DPP tree-reduce across l15 (VALU pipe, result in all lanes)
#pragma unroll
        for (int rt = 0; rt < 2; ++rt)
#pragma unroll
            for (int j = 0; j < 4; ++j)
                part[rt][j] = dpp_red16(part[rt][j]);

        // all-lane epilogue; only l15==0 stores
#pragma unroll
        for (int rt = 0; rt < 2; ++rt) {
            int p = sbase + wid * 8 + rt * 4 + g;
            int qy = p >> 9, qx = p & 511;
            float ar[4];
#pragma unroll
            for (int br = 0; br < 4; ++br) {
                int iy = min(max((qy + ((br & 2) ? 1 : -1)) >> 1, 0), 255);
                int ix = min(max((qx + ((br & 1) ? 1 : -1)) >> 1, 0), 255);
                float ry = (float)(qy - 2 * iy) - 0.5f;
                float rx = (float)(qx - 2 * ix) - 0.5f;
                ar[br] = fabsf(ry * rx) + 1e-9f;
            }
            float val = ((part[rt][0] + bb) * ar[3] + (part[rt][1] + bb) * ar[2]
                       + (part[rt][2] + bb) * ar[1] + (part[rt][3] + bb) * ar[0])
                      / (ar[0] + ar[1] + ar[2] + ar[3]);
            if (l15 == 0) out[p] = val;
        }
    }
}

// ---------- host launcher ----------
extern "C" void kernel_launch(void* const* d_in, const int* in_sizes, int n_in,
                              void* d_out, int out_size, void* d_ws, size_t ws_size,
                              hipStream_t stream) {
    const float* feats2 = (const float*)d_in[0];
    const float* feats4 = (const float*)d_in[1];
    const float* feats32 = (const float*)d_in[2];
    const float* w2 = (const float*)d_in[4];
    const float* s2 = (const float*)d_in[5];
    const float* b2 = (const float*)d_in[6];
    const float* w4 = (const float*)d_in[7];
    const float* s4 = (const float*)d_in[8];
    const float* b4 = (const float*)d_in[9];
    const float* w32 = (const float*)d_in[10];
    const float* s32 = (const float*)d_in[11];
    const float* b32 = (const float*)d_in[12];
    const float* wf = (const float*)d_in[13];
    const float* sf = (const float*)d_in[14];
    const float* bf = (const float*)d_in[15];
    const float* mw0 = (const float*)d_in[16];
    const float* mb0 = (const float*)d_in[17];
    const float* mw1 = (const float*)d_in[18];
    const float* mb1 = (const float*)d_in[19];
    const float* mw2 = (const float*)d_in[20];
    const float* mb2 = (const float*)d_in[21];

    float* a4buf = (float*)d_ws;                          // 128*128*32 f32
    float* a32buf = a4buf + 524288;                       // 16*16*32 f32
    unsigned short* catb16 = (unsigned short*)(a32buf + 8192);   // 65536*96 bf16
    unsigned short* Gbuf = catb16 + 6291456;                     // 65536*128 bf16
    short* w1p = (short*)(Gbuf + 8388608);                // 16384 bf16
    short* w0fp = w1p + 16384;                            // 12288 bf16
    short* wfp = w0fp + 12288;                            // 82944 bf16
    float* corrbuf = (float*)(wfp + 82944);               // 16*128 f32

    k_pack2<<<112, 256, 0, stream>>>(mw0, mw1, w1p, w0fp);
    k_packf<<<324, 256, 0, stream>>>(wf, wfp);
    k_corr<<<8, 256, 0, stream>>>(mw0, mb0, corrbuf);
    k_branch<128><<<2048, 256, 0, stream>>>(feats4, w4, s4, b4, a4buf, 16384);
    k_branch<256><<<32, 256, 0, stream>>>(feats32, w32, s32, b32, a32buf, 256);
    k_cat<<<8192, 256, 0, stream>>>(feats2, w2, s2, b2, a4buf, a32buf, catb16);
    k_fuseG<<<1024, 256, 0, stream>>>(catb16, wfp, sf, bf, w0fp, Gbuf);
    k_mlp9<<<2048, 256, 0, stream>>>(Gbuf, corrbuf, w1p, mb1, mw2, mb2,
                                     (float*)d_out);
}

// Round 11
// 188.482 us; speedup vs baseline: 1.1395x; 1.0720x over previous
//
#include <hip/hip_runtime.h>
#include <hip/hip_bf16.h>

typedef __attribute__((ext_vector_type(8))) short short8v;
typedef __attribute__((ext_vector_type(4))) float float4v;
typedef __attribute__((ext_vector_type(4))) unsigned uint4v;

__device__ __forceinline__ unsigned short f2bf(float x) {
    unsigned u = __float_as_uint(x);
    unsigned r = (u + 0x7fffu + ((u >> 16) & 1u)) >> 16;
    return (unsigned short)r;
}
__device__ __forceinline__ float bf2f(unsigned short u) {
    return __uint_as_float((unsigned)u << 16);
}
__device__ __forceinline__ unsigned cvt_pk_bf16(float lo, float hi) {
    unsigned r;
    asm("v_cvt_pk_bf16_f32 %0, %1, %2" : "=v"(r) : "v"(lo), "v"(hi));
    return r;
}
// sum across each 16-lane row, result in all lanes (VALU-pipe DPP tree).
__device__ __forceinline__ float dpp_red16(float v) {
    int x = __float_as_int(v);
    v += __int_as_float(__builtin_amdgcn_update_dpp(0, x, 0xB1, 0xF, 0xF, false));
    x = __float_as_int(v);
    v += __int_as_float(__builtin_amdgcn_update_dpp(0, x, 0x4E, 0xF, 0xF, false));
    x = __float_as_int(v);
    v += __int_as_float(__builtin_amdgcn_update_dpp(0, x, 0x124, 0xF, 0xF, false));
    x = __float_as_int(v);
    v += __int_as_float(__builtin_amdgcn_update_dpp(0, x, 0x128, 0xF, 0xF, false));
    return v;
}

// ---------- fused prep: pack2 | packf | corr | branch128 | branch256 ----------
// grid 2524: [0,112) pack2, [112,436) packf, [436,444) corr,
// [444,2492) branch<128> (a4), [2492,2524) branch<256> (a32).
__global__ __launch_bounds__(256) void k_prep(
    const float* __restrict__ mw0, const float* __restrict__ mw1,
    const float* __restrict__ wf, const float* __restrict__ mb0,
    const float* __restrict__ feats4, const float* __restrict__ w4,
    const float* __restrict__ s4, const float* __restrict__ b4,
    const float* __restrict__ feats32, const float* __restrict__ w32,
    const float* __restrict__ s32, const float* __restrict__ b32,
    short* __restrict__ w1p, short* __restrict__ w0fp,
    short* __restrict__ wfp, float* __restrict__ corr,
    float* __restrict__ a4buf, float* __restrict__ a32buf) {
    int b = blockIdx.x, t = threadIdx.x;
    if (b < 112) {
        int i = b * 256 + t;                  // 0..28671
        if (i < 16384) {
            int j = i & 7, l = (i >> 3) & 63;
            int nt = (i >> 9) & 7, kt = i >> 12;
            int k = kt * 32 + ((l >> 4) << 3) + j;
            int n = nt * 16 + (l & 15);
            w1p[i] = (short)f2bf(mw1[k * 128 + n]);
        } else {
            int i2 = i - 16384;               // 0..12287
            int j = i2 & 7, l = (i2 >> 3) & 63;
            int nt = (i2 >> 9) & 7, kt = i2 >> 12;
            int k = kt * 32 + ((l >> 4) << 3) + j;
            int n = nt * 16 + (l & 15);
            w0fp[i2] = (short)f2bf(mw0[k * 128 + n]);
        }
    } else if (b < 436) {
        int i = (b - 112) * 256 + t;          // 0..82943
        if (i < 82944) {
            int j = i & 7, l = (i >> 3) & 63;
            int rest = i >> 9;
            int nt = rest % 6, tk = rest / 6;
            int kt = tk % 3, tap = tk / 3;
            int k = kt * 32 + ((l >> 4) << 3) + j;
            int n = nt * 16 + (l & 15);
            wfp[i] = (short)f2bf(wf[((size_t)(tap * 96 + k)) * 96 + n]);
        }
    } else if (b < 444) {
        int i = (b - 436) * 256 + t;          // 0..2047
        int d = i & 127, c = i >> 7;
        float ry = (float)(c >> 2) - 1.5f;
        float rx = (float)(c & 3) - 1.5f;
        corr[i] = fmaf(ry, mw0[96 * 128 + d], fmaf(rx, mw0[97 * 128 + d], mb0[d]));
    } else if (b < 2492) {
        int f = t & 31;
        int pi = (b - 444) * 8 + (t >> 5);    // 0..16383
        const float* xr = feats4 + (size_t)pi * 128;
        float acc = 0.f;
#pragma unroll 4
        for (int c = 0; c < 128; ++c) acc = fmaf(xr[c], w4[c * 32 + f], acc);
        float v = fmaf(acc, s4[f], b4[f]);
        a4buf[(size_t)pi * 32 + f] = fmaxf(v, 0.f);
    } else {
        int f = t & 31;
        int pi = (b - 2492) * 8 + (t >> 5);   // 0..255
        const float* xr = feats32 + (size_t)pi * 256;
        float acc = 0.f;
#pragma unroll 4
        for (int c = 0; c < 256; ++c) acc = fmaf(xr[c], w32[c * 32 + f], acc);
        float v = fmaf(acc, s32[f], b32[f]);
        a32buf[(size_t)pi * 32 + f] = fmaxf(v, 0.f);
    }
}

// ---------- cat builder: a2 (1x1 conv) + bilinear up of a4, a32 -> bf16 ----------
__global__ __launch_bounds__(256) void k_cat(
    const float* __restrict__ feats2, const float* __restrict__ w2,
    const float* __restrict__ s2, const float* __restrict__ b2,
    const float* __restrict__ a4, const float* __restrict__ a32,
    unsigned short* __restrict__ cat) {
    int t = threadIdx.x;
    int f = t & 31;
    int p = blockIdx.x * 8 + (t >> 5);   // 0..65535
    int y = p >> 8, x = p & 255;

    {
        const float* xr = feats2 + (size_t)p * 64;
        float acc = 0.f;
#pragma unroll 4
        for (int c = 0; c < 64; ++c) acc = fmaf(xr[c], w2[c * 32 + f], acc);
        float v = fmaf(acc, s2[f], b2[f]);
        cat[(size_t)p * 96 + f] = f2bf(fmaxf(v, 0.f));
    }
    {
        float sy = fminf(fmaxf(y * 0.5f - 0.25f, 0.f), 127.f);
        float sx = fminf(fmaxf(x * 0.5f - 0.25f, 0.f), 127.f);
        int y0 = (int)sy; float fy = sy - (float)y0; int y1 = min(y0 + 1, 127);
        int x0 = (int)sx; float fx = sx - (float)x0; int x1 = min(x0 + 1, 127);
        float v00 = a4[((size_t)(y0 * 128 + x0)) * 32 + f];
        float v01 = a4[((size_t)(y0 * 128 + x1)) * 32 + f];
        float v10 = a4[((size_t)(y1 * 128 + x0)) * 32 + f];
        float v11 = a4[((size_t)(y1 * 128 + x1)) * 32 + f];
        float vv = (1.f - fy) * ((1.f - fx) * v00 + fx * v01)
                 + fy * ((1.f - fx) * v10 + fx * v11);
        cat[(size_t)p * 96 + 32 + f] = f2bf(vv);
    }
    {
        float sy = fminf(fmaxf((y + 0.5f) * (1.f / 16.f) - 0.5f, 0.f), 15.f);
        float sx = fminf(fmaxf((x + 0.5f) * (1.f / 16.f) - 0.5f, 0.f), 15.f);
        int y0 = (int)sy; float fy = sy - (float)y0; int y1 = min(y0 + 1, 15);
        int x0 = (int)sx; float fx = sx - (float)x0; int x1 = min(x0 + 1, 15);
        float v00 = a32[((size_t)(y0 * 16 + x0)) * 32 + f];
        float v01 = a32[((size_t)(y0 * 16 + x1)) * 32 + f];
        float v10 = a32[((size_t)(y1 * 16 + x0)) * 32 + f];
        float v11 = a32[((size_t)(y1 * 16 + x1)) * 32 + f];
        float vv = (1.f - fy) * ((1.f - fx) * v00 + fx * v01)
                 + fy * ((1.f - fx) * v10 + fx * v11);
        cat[(size_t)p * 96 + 64 + f] = f2bf(vv);
    }
}

// ---------- 3x3 conv (MFMA) + BN + ReLU -> feat (LDS) -> G = feat @ W0f ----------
__global__ __launch_bounds__(256, 4) void k_fuseG(
    const unsigned short* __restrict__ catb, const short* __restrict__ wfp,
    const float* __restrict__ sf, const float* __restrict__ bfb,
    const short* __restrict__ w0fp, unsigned short* __restrict__ G) {
    __shared__ char Xb[100 * 256];
    int t = threadIdx.x;
    int by = (blockIdx.x >> 5) * 8;
    int bx = (blockIdx.x & 31) * 8;

    if (t < 200) {
        int rp = t >> 1, hf = t & 1;
        int gy = by + rp / 10 - 1;
        int gx = bx + rp % 10 - 1;
        bool ok = (gy >= 0 && gy < 256 && gx >= 0 && gx < 256);
        const unsigned short* src = catb + (size_t)(gy * 256 + gx) * 96 + hf * 48;
        int swz = (rp & 7) << 4;
#pragma unroll
        for (int m = 0; m < 6; ++m) {
            short8v v = {0, 0, 0, 0, 0, 0, 0, 0};
            if (ok) v = *(const short8v*)(src + m * 8);
            *(short8v*)(Xb + rp * 256 + (((hf * 6 + m) * 16) ^ swz)) = v;
        }
    }
    __syncthreads();

    int lane = t & 63, wid = t >> 6;
    int wr = wid >> 1, wc = wid & 1;
    int l15 = lane & 15, g = lane >> 4, kb = g * 16;

    float4v acc[2][3];
#pragma unroll
    for (int rb = 0; rb < 2; ++rb)
#pragma unroll
        for (int n = 0; n < 3; ++n)
            acc[rb][n] = (float4v){0.f, 0.f, 0.f, 0.f};

#pragma unroll
    for (int ky = 0; ky < 3; ++ky) {
#pragma unroll
        for (int kx = 0; kx < 3; ++kx) {
#pragma unroll
            for (int kt = 0; kt < 3; ++kt) {
                const short8v* bp = (const short8v*)wfp
                    + (size_t)((((ky * 3 + kx) * 3 + kt) * 6) + wc * 3) * 64 + lane;
                short8v b0 = bp[0], b1 = bp[64], b2 = bp[128];
#pragma unroll
                for (int rb = 0; rb < 2; ++rb) {
                    int R = wr * 32 + rb * 16 + l15;
                    int rp = ((R >> 3) + ky) * 10 + (R & 7) + kx;
                    short8v a = *(short8v*)(Xb + rp * 256
                                 + ((kt * 64 + kb) ^ ((rp & 7) << 4)));
                    acc[rb][0] = __builtin_amdgcn_mfma_f32_16x16x32_bf16(a, b0, acc[rb][0], 0, 0, 0);
                    acc[rb][1] = __builtin_amdgcn_mfma_f32_16x16x32_bf16(a, b1, acc[rb][1], 0, 0, 0);
                    acc[rb][2] = __builtin_amdgcn_mfma_f32_16x16x32_bf16(a, b2, acc[rb][2], 0, 0, 0);
                }
            }
        }
    }
    __syncthreads();   // conv LDS reads done; Xb reusable

    // feat (bf16, BN+ReLU applied) -> Xb as [64 rows][96 ch], pitch 256, swizzled
#pragma unroll
    for (int rb = 0; rb < 2; ++rb) {
#pragma unroll
        for (int n = 0; n < 3; ++n) {
            int ch = (wc * 3 + n) * 16 + l15;
            float sc = sf[ch], bi = bfb[ch];
#pragma unroll
            for (int j = 0; j < 4; ++j) {
                int R = wr * 32 + rb * 16 + g * 4 + j;
                *(short*)(Xb + R * 256 + ((ch * 2) ^ ((R & 7) << 4))) =
                    (short)f2bf(fmaxf(fmaf(acc[rb][n][j], sc, bi), 0.f));
            }
        }
    }
    __syncthreads();

    // G-stage: 64 rows x 128 cols, K=96. Wave wid owns cols [32*wid, 32*wid+32).
    float4v a2[4][2];
#pragma unroll
    for (int r = 0; r < 4; ++r)
#pragma unroll
        for (int n = 0; n < 2; ++n)
            a2[r][n] = (float4v){0.f, 0.f, 0.f, 0.f};

#pragma unroll
    for (int kt = 0; kt < 3; ++kt) {
        const short8v* bp = (const short8v*)w0fp + (kt * 8 + wid * 2) * 64 + lane;
        short8v b0 = bp[0], b1 = bp[64];
#pragma unroll
        for (int r = 0; r < 4; ++r) {
            int row = r * 16 + l15;
            short8v a = *(short8v*)(Xb + row * 256 + ((kt * 64 + kb) ^ ((row & 7) << 4)));
            a2[r][0] = __builtin_amdgcn_mfma_f32_16x16x32_bf16(a, b0, a2[r][0], 0, 0, 0);
            a2[r][1] = __builtin_amdgcn_mfma_f32_16x16x32_bf16(a, b1, a2[r][1], 0, 0, 0);
        }
    }

#pragma unroll
    for (int r = 0; r < 4; ++r) {
#pragma unroll
        for (int n = 0; n < 2; ++n) {
            int colg = (wid * 2 + n) * 16 + l15;
#pragma unroll
            for (int j = 0; j < 4; ++j) {
                int R = r * 16 + g * 4 + j;
                int pix = (by + (R >> 3)) * 256 + bx + (R & 7);
                G[(size_t)pix * 128 + colg] = f2bf(a2[r][n][j]);
            }
        }
    }
}

// ---------- persistent-block fused LIIF query (barrier-free loop) ----------
#define GATHER8(sbase, gvv, cse)                                              \
    {                                                                         \
        _Pragma("unroll")                                                     \
        for (int rt = 0; rt < 2; ++rt) {                                      \
            int row = wid * 32 + rt * 16 + l15;                               \
            int p = (sbase) + (row >> 2);                                     \
            int br = row & 3;                                                 \
            int qy = p >> 9, qx = p & 511;                                    \
            int iy = min(max((qy + ((br & 2) ? 1 : -1)) >> 1, 0), 255);       \
            int ix = min(max((qx + ((br & 1) ? 1 : -1)) >> 1, 0), 255);       \
            cse[rt] = (qy - 2 * iy + 1) * 4 + (qx - 2 * ix + 1);              \
            const unsigned short* gp = G + ((size_t)(iy * 256 + ix)) * 128 + g * 8; \
            _Pragma("unroll")                                                 \
            for (int kt = 0; kt < 4; ++kt)                                    \
                gvv[rt][kt] = *(const short8v*)(gp + kt * 32);                \
        }                                                                     \
    }

__global__ __launch_bounds__(256) void k_mlp10(
    const unsigned short* __restrict__ G,
    const float* __restrict__ corr,
    const short* __restrict__ w1p, const float* __restrict__ b1g,
    const float* __restrict__ w2g, const float* __restrict__ b2g,
    float* __restrict__ out) {
    __shared__ short8v Bs[2048];       // 32KB packed W1
    int t = threadIdx.x;
    int lane = t & 63, wid = t >> 6;
    int l15 = lane & 15, g = lane >> 4;

    // stage W1 into LDS (coalesced, once per block)
    {
        const short8v* wp = (const short8v*)w1p;
#pragma unroll
        for (int i = 0; i < 8; ++i)
            Bs[t + i * 256] = wp[t + i * 256];
    }

    float b1v[8], w2v[8];
#pragma unroll
    for (int nt = 0; nt < 8; ++nt) {
        b1v[nt] = b1g[nt * 16 + l15];
        w2v[nt] = w2g[nt * 16 + l15];
    }
    float bb = b2g[0];

    // XCD-chunked mapping: 8 XCDs x 256 blocks x 4 subtiles x 32 px
    int base0 = (blockIdx.x & 7) * 32768 + (blockIdx.x >> 3) * 128;

    short8v gbuf[2][2][4];
    int cbuf[2][2];
    GATHER8(base0, gbuf[0], cbuf[0]);
    __syncthreads();   // Bs staged

#pragma unroll
    for (int s = 0; s < 4; ++s) {
        const int cur = s & 1, nxt = cur ^ 1;
        int sbase = base0 + s * 32;
        if (s < 3) GATHER8(sbase + 32, gbuf[nxt], cbuf[nxt]);

        // build A-frags: H = relu(G + corr[case]), packed bf16
        short8v afrag[2][4];
#pragma unroll
        for (int rt = 0; rt < 2; ++rt) {
            const float* cp = corr + cbuf[cur][rt] * 128 + g * 8;
#pragma unroll
            for (int kt = 0; kt < 4; ++kt) {
                short8v gv = gbuf[cur][rt][kt];
                float4 c0 = *(const float4*)(cp + kt * 32);
                float4 c1 = *(const float4*)(cp + kt * 32 + 4);
                uint4v u;
                u[0] = cvt_pk_bf16(fmaxf(bf2f((unsigned short)gv[0]) + c0.x, 0.f),
                                   fmaxf(bf2f((unsigned short)gv[1]) + c0.y, 0.f));
                u[1] = cvt_pk_bf16(fmaxf(bf2f((unsigned short)gv[2]) + c0.z, 0.f),
                                   fmaxf(bf2f((unsigned short)gv[3]) + c0.w, 0.f));
                u[2] = cvt_pk_bf16(fmaxf(bf2f((unsigned short)gv[4]) + c1.x, 0.f),
                                   fmaxf(bf2f((unsigned short)gv[5]) + c1.y, 0.f));
                u[3] = cvt_pk_bf16(fmaxf(bf2f((unsigned short)gv[6]) + c1.z, 0.f),
                                   fmaxf(bf2f((unsigned short)gv[7]) + c1.w, 0.f));
                afrag[rt][kt] = __builtin_bit_cast(short8v, u);
            }
        }

        // layer 1 MFMA (b1 folded into C-init) + fused layer 2
        float part[2][4];
#pragma unroll
        for (int rt = 0; rt < 2; ++rt)
#pragma unroll
            for (int j = 0; j < 4; ++j) part[rt][j] = 0.f;

#pragma unroll
        for (int nh = 0; nh < 2; ++nh) {
            float4v acc[2][4];
#pragma unroll
            for (int rt = 0; rt < 2; ++rt)
#pragma unroll
                for (int n = 0; n < 4; ++n) {
                    float bv = b1v[nh * 4 + n];
                    acc[rt][n] = (float4v){bv, bv, bv, bv};
                }
            __builtin_amdgcn_s_setprio(1);
#pragma unroll
            for (int kt = 0; kt < 4; ++kt) {
#pragma unroll
                for (int n = 0; n < 4; ++n) {
                    short8v b = Bs[(kt * 8 + nh * 4 + n) * 64 + lane];
                    acc[0][n] = __builtin_amdgcn_mfma_f32_16x16x32_bf16(afrag[0][kt], b, acc[0][n], 0, 0, 0);
                    acc[1][n] = __builtin_amdgcn_mfma_f32_16x16x32_bf16(afrag[1][kt], b, acc[1][n], 0, 0, 0);
                }
            }
            __builtin_amdgcn_s_setprio(0);
#pragma unroll
            for (int rt = 0; rt < 2; ++rt)
#pragma unroll
                for (int n = 0; n < 4; ++n)
#pragma unroll
                    for (int j = 0; j < 4; ++j)
                        part[rt][j] += fmaxf(acc[rt][n][j], 0.f) * w2v[nh * 4 + n];
        }

        // DPP tree-reduce across l15 (VALU pipe, result in all lanes)
#pragma unroll
        for (int rt = 0; rt < 2; ++rt)
#pragma unroll
            for (int j = 0; j < 4; ++j)
                part[rt][j] = dpp_red16(part[rt][j]);

        // all-lane epilogue; only l15==0 stores
#pragma unroll
        for (int rt = 0; rt < 2; ++rt) {
            int p = sbase + wid * 8 + rt * 4 + g;
            int qy = p >> 9, qx = p & 511;
            float ar[4];
#pragma unroll
            for (int br = 0; br < 4; ++br) {
                int iy = min(max((qy + ((br & 2) ? 1 : -1)) >> 1, 0), 255);
                int ix = min(max((qx + ((br & 1) ? 1 : -1)) >> 1, 0), 255);
                float ry = (float)(qy - 2 * iy) - 0.5f;
                float rx = (float)(qx - 2 * ix) - 0.5f;
                ar[br] = fabsf(ry * rx) + 1e-9f;
            }
            float val = ((part[rt][0] + bb) * ar[3] + (part[rt][1] + bb) * ar[2]
                       + (part[rt][2] + bb) * ar[1] + (part[rt][3] + bb) * ar[0])
                      / (ar[0] + ar[1] + ar[2] + ar[3]);
            if (l15 == 0) out[p] = val;
        }
    }
}

// ---------- host launcher ----------
extern "C" void kernel_launch(void* const* d_in, const int* in_sizes, int n_in,
                              void* d_out, int out_size, void* d_ws, size_t ws_size,
                              hipStream_t stream) {
    const float* feats2 = (const float*)d_in[0];
    const float* feats4 = (const float*)d_in[1];
    const float* feats32 = (const float*)d_in[2];
    const float* w2 = (const float*)d_in[4];
    const float* s2 = (const float*)d_in[5];
    const float* b2 = (const float*)d_in[6];
    const float* w4 = (const float*)d_in[7];
    const float* s4 = (const float*)d_in[8];
    const float* b4 = (const float*)d_in[9];
    const float* w32 = (const float*)d_in[10];
    const float* s32 = (const float*)d_in[11];
    const float* b32 = (const float*)d_in[12];
    const float* wf = (const float*)d_in[13];
    const float* sf = (const float*)d_in[14];
    const float* bf = (const float*)d_in[15];
    const float* mw0 = (const float*)d_in[16];
    const float* mb0 = (const float*)d_in[17];
    const float* mw1 = (const float*)d_in[18];
    const float* mb1 = (const float*)d_in[19];
    const float* mw2 = (const float*)d_in[20];
    const float* mb2 = (const float*)d_in[21];

    float* a4buf = (float*)d_ws;                          // 128*128*32 f32
    float* a32buf = a4buf + 524288;                       // 16*16*32 f32
    unsigned short* catb16 = (unsigned short*)(a32buf + 8192);   // 65536*96 bf16
    unsigned short* Gbuf = catb16 + 6291456;                     // 65536*128 bf16
    short* w1p = (short*)(Gbuf + 8388608);                // 16384 bf16
    short* w0fp = w1p + 16384;                            // 12288 bf16
    short* wfp = w0fp + 12288;                            // 82944 bf16
    float* corrbuf = (float*)(wfp + 82944);               // 16*128 f32

    k_prep<<<2524, 256, 0, stream>>>(mw0, mw1, wf, mb0,
                                     feats4, w4, s4, b4,
                                     feats32, w32, s32, b32,
                                     w1p, w0fp, wfp, corrbuf, a4buf, a32buf);
    k_cat<<<8192, 256, 0, stream>>>(feats2, w2, s2, b2, a4buf, a32buf, catb16);
    k_fuseG<<<1024, 256, 0, stream>>>(catb16, wfp, sf, bf, w0fp, Gbuf);
    k_mlp10<<<2048, 256, 0, stream>>>(Gbuf, corrbuf, w1p, mb1, mw2, mb2,
                                      (float*)d_out);
}

// Round 12
// 185.216 us; speedup vs baseline: 1.1596x; 1.0176x over previous
//
#include <hip/hip_runtime.h>
#include <hip/hip_bf16.h>

typedef __attribute__((ext_vector_type(8))) short short8v;
typedef __attribute__((ext_vector_type(4))) float float4v;
typedef __attribute__((ext_vector_type(4))) unsigned uint4v;

__device__ __forceinline__ unsigned short f2bf(float x) {
    unsigned u = __float_as_uint(x);
    unsigned r = (u + 0x7fffu + ((u >> 16) & 1u)) >> 16;
    return (unsigned short)r;
}
__device__ __forceinline__ float bf2f(unsigned short u) {
    return __uint_as_float((unsigned)u << 16);
}
__device__ __forceinline__ unsigned cvt_pk_bf16(float lo, float hi) {
    unsigned r;
    asm("v_cvt_pk_bf16_f32 %0, %1, %2" : "=v"(r) : "v"(lo), "v"(hi));
    return r;
}
// sum across each 16-lane row, result in all lanes (VALU-pipe DPP tree).
__device__ __forceinline__ float dpp_red16(float v) {
    int x = __float_as_int(v);
    v += __int_as_float(__builtin_amdgcn_update_dpp(0, x, 0xB1, 0xF, 0xF, false));
    x = __float_as_int(v);
    v += __int_as_float(__builtin_amdgcn_update_dpp(0, x, 0x4E, 0xF, 0xF, false));
    x = __float_as_int(v);
    v += __int_as_float(__builtin_amdgcn_update_dpp(0, x, 0x124, 0xF, 0xF, false));
    x = __float_as_int(v);
    v += __int_as_float(__builtin_amdgcn_update_dpp(0, x, 0x128, 0xF, 0xF, false));
    return v;
}

// ---------- fused prep: pack2 | packf | corr | branch128 | branch256 ----------
__global__ __launch_bounds__(256) void k_prep(
    const float* __restrict__ mw0, const float* __restrict__ mw1,
    const float* __restrict__ wf, const float* __restrict__ mb0,
    const float* __restrict__ feats4, const float* __restrict__ w4,
    const float* __restrict__ s4, const float* __restrict__ b4,
    const float* __restrict__ feats32, const float* __restrict__ w32,
    const float* __restrict__ s32, const float* __restrict__ b32,
    short* __restrict__ w1p, short* __restrict__ w0fp,
    short* __restrict__ wfp, float* __restrict__ corr,
    float* __restrict__ a4buf, float* __restrict__ a32buf) {
    int b = blockIdx.x, t = threadIdx.x;
    if (b < 112) {
        int i = b * 256 + t;                  // 0..28671
        if (i < 16384) {
            int j = i & 7, l = (i >> 3) & 63;
            int nt = (i >> 9) & 7, kt = i >> 12;
            int k = kt * 32 + ((l >> 4) << 3) + j;
            int n = nt * 16 + (l & 15);
            w1p[i] = (short)f2bf(mw1[k * 128 + n]);
        } else {
            int i2 = i - 16384;               // 0..12287
            int j = i2 & 7, l = (i2 >> 3) & 63;
            int nt = (i2 >> 9) & 7, kt = i2 >> 12;
            int k = kt * 32 + ((l >> 4) << 3) + j;
            int n = nt * 16 + (l & 15);
            w0fp[i2] = (short)f2bf(mw0[k * 128 + n]);
        }
    } else if (b < 436) {
        int i = (b - 112) * 256 + t;          // 0..82943
        if (i < 82944) {
            int j = i & 7, l = (i >> 3) & 63;
            int rest = i >> 9;
            int nt = rest % 6, tk = rest / 6;
            int kt = tk % 3, tap = tk / 3;
            int k = kt * 32 + ((l >> 4) << 3) + j;
            int n = nt * 16 + (l & 15);
            wfp[i] = (short)f2bf(wf[((size_t)(tap * 96 + k)) * 96 + n]);
        }
    } else if (b < 444) {
        int i = (b - 436) * 256 + t;          // 0..2047
        int d = i & 127, c = i >> 7;
        float ry = (float)(c >> 2) - 1.5f;
        float rx = (float)(c & 3) - 1.5f;
        corr[i] = fmaf(ry, mw0[96 * 128 + d], fmaf(rx, mw0[97 * 128 + d], mb0[d]));
    } else if (b < 2492) {
        int f = t & 31;
        int pi = (b - 444) * 8 + (t >> 5);    // 0..16383
        const float* xr = feats4 + (size_t)pi * 128;
        float acc = 0.f;
#pragma unroll 4
        for (int c = 0; c < 128; ++c) acc = fmaf(xr[c], w4[c * 32 + f], acc);
        float v = fmaf(acc, s4[f], b4[f]);
        a4buf[(size_t)pi * 32 + f] = fmaxf(v, 0.f);
    } else {
        int f = t & 31;
        int pi = (b - 2492) * 8 + (t >> 5);   // 0..255
        const float* xr = feats32 + (size_t)pi * 256;
        float acc = 0.f;
#pragma unroll 4
        for (int c = 0; c < 256; ++c) acc = fmaf(xr[c], w32[c * 32 + f], acc);
        float v = fmaf(acc, s32[f], b32[f]);
        a32buf[(size_t)pi * 32 + f] = fmaxf(v, 0.f);
    }
}

// ---------- cat builder: a2 (1x1 conv) + bilinear up of a4, a32 -> bf16 ----------
__global__ __launch_bounds__(256) void k_cat(
    const float* __restrict__ feats2, const float* __restrict__ w2,
    const float* __restrict__ s2, const float* __restrict__ b2,
    const float* __restrict__ a4, const float* __restrict__ a32,
    unsigned short* __restrict__ cat) {
    int t = threadIdx.x;
    int f = t & 31;
    int p = blockIdx.x * 8 + (t >> 5);   // 0..65535
    int y = p >> 8, x = p & 255;

    {
        const float* xr = feats2 + (size_t)p * 64;
        float acc = 0.f;
#pragma unroll 4
        for (int c = 0; c < 64; ++c) acc = fmaf(xr[c], w2[c * 32 + f], acc);
        float v = fmaf(acc, s2[f], b2[f]);
        cat[(size_t)p * 96 + f] = f2bf(fmaxf(v, 0.f));
    }
    {
        float sy = fminf(fmaxf(y * 0.5f - 0.25f, 0.f), 127.f);
        float sx = fminf(fmaxf(x * 0.5f - 0.25f, 0.f), 127.f);
        int y0 = (int)sy; float fy = sy - (float)y0; int y1 = min(y0 + 1, 127);
        int x0 = (int)sx; float fx = sx - (float)x0; int x1 = min(x0 + 1, 127);
        float v00 = a4[((size_t)(y0 * 128 + x0)) * 32 + f];
        float v01 = a4[((size_t)(y0 * 128 + x1)) * 32 + f];
        float v10 = a4[((size_t)(y1 * 128 + x0)) * 32 + f];
        float v11 = a4[((size_t)(y1 * 128 + x1)) * 32 + f];
        float vv = (1.f - fy) * ((1.f - fx) * v00 + fx * v01)
                 + fy * ((1.f - fx) * v10 + fx * v11);
        cat[(size_t)p * 96 + 32 + f] = f2bf(vv);
    }
    {
        float sy = fminf(fmaxf((y + 0.5f) * (1.f / 16.f) - 0.5f, 0.f), 15.f);
        float sx = fminf(fmaxf((x + 0.5f) * (1.f / 16.f) - 0.5f, 0.f), 15.f);
        int y0 = (int)sy; float fy = sy - (float)y0; int y1 = min(y0 + 1, 15);
        int x0 = (int)sx; float fx = sx - (float)x0; int x1 = min(x0 + 1, 15);
        float v00 = a32[((size_t)(y0 * 16 + x0)) * 32 + f];
        float v01 = a32[((size_t)(y0 * 16 + x1)) * 32 + f];
        float v10 = a32[((size_t)(y1 * 16 + x0)) * 32 + f];
        float v11 = a32[((size_t)(y1 * 16 + x1)) * 32 + f];
        float vv = (1.f - fy) * ((1.f - fx) * v00 + fx * v01)
                 + fy * ((1.f - fx) * v10 + fx * v11);
        cat[(size_t)p * 96 + 64 + f] = f2bf(vv);
    }
}

// ---------- 3x3 conv (MFMA) + BN + ReLU -> feat (LDS) -> G = feat @ W0f ----------
__global__ __launch_bounds__(256, 4) void k_fuseG(
    const unsigned short* __restrict__ catb, const short* __restrict__ wfp,
    const float* __restrict__ sf, const float* __restrict__ bfb,
    const short* __restrict__ w0fp, unsigned short* __restrict__ G) {
    __shared__ char Xb[100 * 256];
    int t = threadIdx.x;
    int by = (blockIdx.x >> 5) * 8;
    int bx = (blockIdx.x & 31) * 8;

    if (t < 200) {
        int rp = t >> 1, hf = t & 1;
        int gy = by + rp / 10 - 1;
        int gx = bx + rp % 10 - 1;
        bool ok = (gy >= 0 && gy < 256 && gx >= 0 && gx < 256);
        const unsigned short* src = catb + (size_t)(gy * 256 + gx) * 96 + hf * 48;
        int swz = (rp & 7) << 4;
#pragma unroll
        for (int m = 0; m < 6; ++m) {
            short8v v = {0, 0, 0, 0, 0, 0, 0, 0};
            if (ok) v = *(const short8v*)(src + m * 8);
            *(short8v*)(Xb + rp * 256 + (((hf * 6 + m) * 16) ^ swz)) = v;
        }
    }
    __syncthreads();

    int lane = t & 63, wid = t >> 6;
    int wr = wid >> 1, wc = wid & 1;
    int l15 = lane & 15, g = lane >> 4, kb = g * 16;

    float4v acc[2][3];
#pragma unroll
    for (int rb = 0; rb < 2; ++rb)
#pragma unroll
        for (int n = 0; n < 3; ++n)
            acc[rb][n] = (float4v){0.f, 0.f, 0.f, 0.f};

#pragma unroll
    for (int ky = 0; ky < 3; ++ky) {
#pragma unroll
        for (int kx = 0; kx < 3; ++kx) {
#pragma unroll
            for (int kt = 0; kt < 3; ++kt) {
                const short8v* bp = (const short8v*)wfp
                    + (size_t)((((ky * 3 + kx) * 3 + kt) * 6) + wc * 3) * 64 + lane;
                short8v b0 = bp[0], b1 = bp[64], b2 = bp[128];
#pragma unroll
                for (int rb = 0; rb < 2; ++rb) {
                    int R = wr * 32 + rb * 16 + l15;
                    int rp = ((R >> 3) + ky) * 10 + (R & 7) + kx;
                    short8v a = *(short8v*)(Xb + rp * 256
                                 + ((kt * 64 + kb) ^ ((rp & 7) << 4)));
                    acc[rb][0] = __builtin_amdgcn_mfma_f32_16x16x32_bf16(a, b0, acc[rb][0], 0, 0, 0);
                    acc[rb][1] = __builtin_amdgcn_mfma_f32_16x16x32_bf16(a, b1, acc[rb][1], 0, 0, 0);
                    acc[rb][2] = __builtin_amdgcn_mfma_f32_16x16x32_bf16(a, b2, acc[rb][2], 0, 0, 0);
                }
            }
        }
    }
    __syncthreads();   // conv LDS reads done; Xb reusable

    // feat (bf16, BN+ReLU applied) -> Xb as [64 rows][96 ch], pitch 256, swizzled
#pragma unroll
    for (int rb = 0; rb < 2; ++rb) {
#pragma unroll
        for (int n = 0; n < 3; ++n) {
            int ch = (wc * 3 + n) * 16 + l15;
            float sc = sf[ch], bi = bfb[ch];
#pragma unroll
            for (int j = 0; j < 4; ++j) {
                int R = wr * 32 + rb * 16 + g * 4 + j;
                *(short*)(Xb + R * 256 + ((ch * 2) ^ ((R & 7) << 4))) =
                    (short)f2bf(fmaxf(fmaf(acc[rb][n][j], sc, bi), 0.f));
            }
        }
    }
    __syncthreads();

    // G-stage: 64 rows x 128 cols, K=96. Wave wid owns cols [32*wid, 32*wid+32).
    float4v a2[4][2];
#pragma unroll
    for (int r = 0; r < 4; ++r)
#pragma unroll
        for (int n = 0; n < 2; ++n)
            a2[r][n] = (float4v){0.f, 0.f, 0.f, 0.f};

#pragma unroll
    for (int kt = 0; kt < 3; ++kt) {
        const short8v* bp = (const short8v*)w0fp + (kt * 8 + wid * 2) * 64 + lane;
        short8v b0 = bp[0], b1 = bp[64];
#pragma unroll
        for (int r = 0; r < 4; ++r) {
            int row = r * 16 + l15;
            short8v a = *(short8v*)(Xb + row * 256 + ((kt * 64 + kb) ^ ((row & 7) << 4)));
            a2[r][0] = __builtin_amdgcn_mfma_f32_16x16x32_bf16(a, b0, a2[r][0], 0, 0, 0);
            a2[r][1] = __builtin_amdgcn_mfma_f32_16x16x32_bf16(a, b1, a2[r][1], 0, 0, 0);
        }
    }

#pragma unroll
    for (int r = 0; r < 4; ++r) {
#pragma unroll
        for (int n = 0; n < 2; ++n) {
            int colg = (wid * 2 + n) * 16 + l15;
#pragma unroll
            for (int j = 0; j < 4; ++j) {
                int R = r * 16 + g * 4 + j;
                int pix = (by + (R >> 3)) * 256 + bx + (R & 7);
                G[(size_t)pix * 128 + colg] = f2bf(a2[r][n][j]);
            }
        }
    }
}

// ---------- 8-wave, <=64-VGPR fused LIIF query ----------
// 2048 blocks x 512 thr (8 waves). Each wave: 4 units x 16 MLP rows (4 px).
// Bs (32KB W1) + b1/w2 staged in LDS, shared by 8 waves -> 4 blocks/CU
// = 32 waves/CU if VGPR <= 64 (launch_bounds(512,8) pins the cap).
// No register double-buffer: 8-wave TLP hides gather latency.
__global__ __launch_bounds__(512, 8) void k_mlp11(
    const unsigned short* __restrict__ G,
    const float* __restrict__ corr,
    const short* __restrict__ w1p, const float* __restrict__ b1g,
    const float* __restrict__ w2g, const float* __restrict__ b2g,
    float* __restrict__ out) {
    __shared__ short8v Bs[2048];       // 32KB packed W1
    __shared__ float b1s[128], w2s[128];
    int t = threadIdx.x;
    int lane = t & 63, wid = t >> 6;   // wid 0..7
    int l15 = lane & 15, g = lane >> 4;

    {
        const short8v* wp = (const short8v*)w1p;
#pragma unroll
        for (int i = 0; i < 4; ++i)
            Bs[t + i * 512] = wp[t + i * 512];
        if (t < 128) b1s[t] = b1g[t];
        else if (t < 256) w2s[t - 128] = w2g[t - 128];
    }
    float bb = b2g[0];
    __syncthreads();

    // XCD-chunked: 8 XCDs x 256 blocks x (8 waves x 4 units)
    int base_u = (blockIdx.x & 7) * 8192 + (blockIdx.x >> 3) * 32 + wid * 4;

#pragma unroll
    for (int s = 0; s < 4; ++s) {
        int U = base_u + s;
        // this lane's MLP row and its gather cell (exact int coord path)
        int row = U * 16 + l15;
        int p = row >> 2, br = row & 3;
        int qy = p >> 9, qx = p & 511;
        int iy = min(max((qy + ((br & 2) ? 1 : -1)) >> 1, 0), 255);
        int ix = min(max((qx + ((br & 1) ? 1 : -1)) >> 1, 0), 255);
        int cse = (qy - 2 * iy + 1) * 4 + (qx - 2 * ix + 1);
        const unsigned short* gp = G + ((size_t)(iy * 256 + ix)) * 128 + g * 8;
        const float* cp = corr + cse * 128 + g * 8;

        // build A-frags: H = relu(G + corr[case]) packed bf16 (streamed per kt)
        short8v afrag[4];
#pragma unroll
        for (int kt = 0; kt < 4; ++kt) {
            short8v gv = *(const short8v*)(gp + kt * 32);
            float4 c0 = *(const float4*)(cp + kt * 32);
            float4 c1 = *(const float4*)(cp + kt * 32 + 4);
            uint4v u;
            u[0] = cvt_pk_bf16(fmaxf(bf2f((unsigned short)gv[0]) + c0.x, 0.f),
                               fmaxf(bf2f((unsigned short)gv[1]) + c0.y, 0.f));
            u[1] = cvt_pk_bf16(fmaxf(bf2f((unsigned short)gv[2]) + c0.z, 0.f),
                               fmaxf(bf2f((unsigned short)gv[3]) + c0.w, 0.f));
            u[2] = cvt_pk_bf16(fmaxf(bf2f((unsigned short)gv[4]) + c1.x, 0.f),
                               fmaxf(bf2f((unsigned short)gv[5]) + c1.y, 0.f));
            u[3] = cvt_pk_bf16(fmaxf(bf2f((unsigned short)gv[6]) + c1.z, 0.f),
                               fmaxf(bf2f((unsigned short)gv[7]) + c1.w, 0.f));
            afrag[kt] = __builtin_bit_cast(short8v, u);
        }

        // layer 1 MFMA (b1 in C-init) + fused layer 2, nh-halved (acc = 16 regs)
        float part[4] = {0.f, 0.f, 0.f, 0.f};
#pragma unroll
        for (int nh = 0; nh < 2; ++nh) {
            float4v acc[4];
            float wv[4];
#pragma unroll
            for (int n = 0; n < 4; ++n) {
                int colg = (nh * 4 + n) * 16 + l15;
                float bv = b1s[colg];
                wv[n] = w2s[colg];
                acc[n] = (float4v){bv, bv, bv, bv};
            }
            __builtin_amdgcn_s_setprio(1);
#pragma unroll
            for (int kt = 0; kt < 4; ++kt) {
#pragma unroll
                for (int n = 0; n < 4; ++n) {
                    short8v b = Bs[(kt * 8 + nh * 4 + n) * 64 + lane];
                    acc[n] = __builtin_amdgcn_mfma_f32_16x16x32_bf16(afrag[kt], b, acc[n], 0, 0, 0);
                }
            }
            __builtin_amdgcn_s_setprio(0);
#pragma unroll
            for (int n = 0; n < 4; ++n)
#pragma unroll
                for (int j = 0; j < 4; ++j)
                    part[j] += fmaxf(acc[n][j], 0.f) * wv[n];
        }

        // DPP tree-reduce across the 16-lane group (result in all lanes)
#pragma unroll
        for (int j = 0; j < 4; ++j) part[j] = dpp_red16(part[j]);

        // epilogue: group g owns pixel U*4+g (D rows g*4+j = branches j)
        int pp = U * 4 + g;
        int qy2 = pp >> 9, qx2 = pp & 511;
        float ar[4];
#pragma unroll
        for (int b2 = 0; b2 < 4; ++b2) {
            int iy2 = min(max((qy2 + ((b2 & 2) ? 1 : -1)) >> 1, 0), 255);
            int ix2 = min(max((qx2 + ((b2 & 1) ? 1 : -1)) >> 1, 0), 255);
            float ry = (float)(qy2 - 2 * iy2) - 0.5f;
            float rx = (float)(qx2 - 2 * ix2) - 0.5f;
            ar[b2] = fabsf(ry * rx) + 1e-9f;
        }
        float val = ((part[0] + bb) * ar[3] + (part[1] + bb) * ar[2]
                   + (part[2] + bb) * ar[1] + (part[3] + bb) * ar[0])
                  / (ar[0] + ar[1] + ar[2] + ar[3]);
        if (l15 == 0) out[pp] = val;
    }
}

// ---------- host launcher ----------
extern "C" void kernel_launch(void* const* d_in, const int* in_sizes, int n_in,
                              void* d_out, int out_size, void* d_ws, size_t ws_size,
                              hipStream_t stream) {
    const float* feats2 = (const float*)d_in[0];
    const float* feats4 = (const float*)d_in[1];
    const float* feats32 = (const float*)d_in[2];
    const float* w2 = (const float*)d_in[4];
    const float* s2 = (const float*)d_in[5];
    const float* b2 = (const float*)d_in[6];
    const float* w4 = (const float*)d_in[7];
    const float* s4 = (const float*)d_in[8];
    const float* b4 = (const float*)d_in[9];
    const float* w32 = (const float*)d_in[10];
    const float* s32 = (const float*)d_in[11];
    const float* b32 = (const float*)d_in[12];
    const float* wf = (const float*)d_in[13];
    const float* sf = (const float*)d_in[14];
    const float* bf = (const float*)d_in[15];
    const float* mw0 = (const float*)d_in[16];
    const float* mb0 = (const float*)d_in[17];
    const float* mw1 = (const float*)d_in[18];
    const float* mb1 = (const float*)d_in[19];
    const float* mw2 = (const float*)d_in[20];
    const float* mb2 = (const float*)d_in[21];

    float* a4buf = (float*)d_ws;                          // 128*128*32 f32
    float* a32buf = a4buf + 524288;                       // 16*16*32 f32
    unsigned short* catb16 = (unsigned short*)(a32buf + 8192);   // 65536*96 bf16
    unsigned short* Gbuf = catb16 + 6291456;                     // 65536*128 bf16
    short* w1p = (short*)(Gbuf + 8388608);                // 16384 bf16
    short* w0fp = w1p + 16384;                            // 12288 bf16
    short* wfp = w0fp + 12288;                            // 82944 bf16
    float* corrbuf = (float*)(wfp + 82944);               // 16*128 f32

    k_prep<<<2524, 256, 0, stream>>>(mw0, mw1, wf, mb0,
                                     feats4, w4, s4, b4,
                                     feats32, w32, s32, b32,
                                     w1p, w0fp, wfp, corrbuf, a4buf, a32buf);
    k_cat<<<8192, 256, 0, stream>>>(feats2, w2, s2, b2, a4buf, a32buf, catb16);
    k_fuseG<<<1024, 256, 0, stream>>>(catb16, wfp, sf, bf, w0fp, Gbuf);
    k_mlp11<<<2048, 512, 0, stream>>>(Gbuf, corrbuf, w1p, mb1, mw2, mb2,
                                      (float*)d_out);
}

// Round 13
// 134.571 us; speedup vs baseline: 1.5961x; 1.3763x over previous
//
#include <hip/hip_runtime.h>
#include <hip/hip_bf16.h>

typedef __attribute__((ext_vector_type(8))) short short8v;
typedef __attribute__((ext_vector_type(4))) float float4v;
typedef __attribute__((ext_vector_type(4))) unsigned uint4v;

__device__ __forceinline__ unsigned short f2bf(float x) {
    unsigned u = __float_as_uint(x);
    unsigned r = (u + 0x7fffu + ((u >> 16) & 1u)) >> 16;
    return (unsigned short)r;
}
__device__ __forceinline__ float bf2f(unsigned short u) {
    return __uint_as_float((unsigned)u << 16);
}
__device__ __forceinline__ unsigned cvt_pk_bf16(float lo, float hi) {
    unsigned r;
    asm("v_cvt_pk_bf16_f32 %0, %1, %2" : "=v"(r) : "v"(lo), "v"(hi));
    return r;
}
// sum across each 16-lane row, result in all lanes (VALU-pipe DPP tree).
__device__ __forceinline__ float dpp_red16(float v) {
    int x = __float_as_int(v);
    v += __int_as_float(__builtin_amdgcn_update_dpp(0, x, 0xB1, 0xF, 0xF, false));
    x = __float_as_int(v);
    v += __int_as_float(__builtin_amdgcn_update_dpp(0, x, 0x4E, 0xF, 0xF, false));
    x = __float_as_int(v);
    v += __int_as_float(__builtin_amdgcn_update_dpp(0, x, 0x124, 0xF, 0xF, false));
    x = __float_as_int(v);
    v += __int_as_float(__builtin_amdgcn_update_dpp(0, x, 0x128, 0xF, 0xF, false));
    return v;
}

// ---------- fused prep: pack2 | packf | corr | branch128 | branch256 ----------
__global__ __launch_bounds__(256) void k_prep(
    const float* __restrict__ mw0, const float* __restrict__ mw1,
    const float* __restrict__ wf, const float* __restrict__ mb0,
    const float* __restrict__ feats4, const float* __restrict__ w4,
    const float* __restrict__ s4, const float* __restrict__ b4,
    const float* __restrict__ feats32, const float* __restrict__ w32,
    const float* __restrict__ s32, const float* __restrict__ b32,
    short* __restrict__ w1p, short* __restrict__ w0fp,
    short* __restrict__ wfp, float* __restrict__ corr,
    float* __restrict__ a4buf, float* __restrict__ a32buf) {
    int b = blockIdx.x, t = threadIdx.x;
    if (b < 112) {
        int i = b * 256 + t;                  // 0..28671
        if (i < 16384) {
            int j = i & 7, l = (i >> 3) & 63;
            int nt = (i >> 9) & 7, kt = i >> 12;
            int k = kt * 32 + ((l >> 4) << 3) + j;
            int n = nt * 16 + (l & 15);
            w1p[i] = (short)f2bf(mw1[k * 128 + n]);
        } else {
            int i2 = i - 16384;               // 0..12287
            int j = i2 & 7, l = (i2 >> 3) & 63;
            int nt = (i2 >> 9) & 7, kt = i2 >> 12;
            int k = kt * 32 + ((l >> 4) << 3) + j;
            int n = nt * 16 + (l & 15);
            w0fp[i2] = (short)f2bf(mw0[k * 128 + n]);
        }
    } else if (b < 436) {
        int i = (b - 112) * 256 + t;          // 0..82943
        if (i < 82944) {
            int j = i & 7, l = (i >> 3) & 63;
            int rest = i >> 9;
            int nt = rest % 6, tk = rest / 6;
            int kt = tk % 3, tap = tk / 3;
            int k = kt * 32 + ((l >> 4) << 3) + j;
            int n = nt * 16 + (l & 15);
            wfp[i] = (short)f2bf(wf[((size_t)(tap * 96 + k)) * 96 + n]);
        }
    } else if (b < 444) {
        int i = (b - 436) * 256 + t;          // 0..2047
        int d = i & 127, c = i >> 7;
        float ry = (float)(c >> 2) - 1.5f;
        float rx = (float)(c & 3) - 1.5f;
        corr[i] = fmaf(ry, mw0[96 * 128 + d], fmaf(rx, mw0[97 * 128 + d], mb0[d]));
    } else if (b < 2492) {
        int f = t & 31;
        int pi = (b - 444) * 8 + (t >> 5);    // 0..16383
        const float* xr = feats4 + (size_t)pi * 128;
        float acc = 0.f;
#pragma unroll 4
        for (int c = 0; c < 128; ++c) acc = fmaf(xr[c], w4[c * 32 + f], acc);
        float v = fmaf(acc, s4[f], b4[f]);
        a4buf[(size_t)pi * 32 + f] = fmaxf(v, 0.f);
    } else {
        int f = t & 31;
        int pi = (b - 2492) * 8 + (t >> 5);   // 0..255
        const float* xr = feats32 + (size_t)pi * 256;
        float acc = 0.f;
#pragma unroll 4
        for (int c = 0; c < 256; ++c) acc = fmaf(xr[c], w32[c * 32 + f], acc);
        float v = fmaf(acc, s32[f], b32[f]);
        a32buf[(size_t)pi * 32 + f] = fmaxf(v, 0.f);
    }
}

// ---------- cat builder: a2 (1x1 conv) + bilinear up of a4, a32 -> bf16 ----------
__global__ __launch_bounds__(256) void k_cat(
    const float* __restrict__ feats2, const float* __restrict__ w2,
    const float* __restrict__ s2, const float* __restrict__ b2,
    const float* __restrict__ a4, const float* __restrict__ a32,
    unsigned short* __restrict__ cat) {
    int t = threadIdx.x;
    int f = t & 31;
    int p = blockIdx.x * 8 + (t >> 5);   // 0..65535
    int y = p >> 8, x = p & 255;

    {
        const float* xr = feats2 + (size_t)p * 64;
        float acc = 0.f;
#pragma unroll 4
        for (int c = 0; c < 64; ++c) acc = fmaf(xr[c], w2[c * 32 + f], acc);
        float v = fmaf(acc, s2[f], b2[f]);
        cat[(size_t)p * 96 + f] = f2bf(fmaxf(v, 0.f));
    }
    {
        float sy = fminf(fmaxf(y * 0.5f - 0.25f, 0.f), 127.f);
        float sx = fminf(fmaxf(x * 0.5f - 0.25f, 0.f), 127.f);
        int y0 = (int)sy; float fy = sy - (float)y0; int y1 = min(y0 + 1, 127);
        int x0 = (int)sx; float fx = sx - (float)x0; int x1 = min(x0 + 1, 127);
        float v00 = a4[((size_t)(y0 * 128 + x0)) * 32 + f];
        float v01 = a4[((size_t)(y0 * 128 + x1)) * 32 + f];
        float v10 = a4[((size_t)(y1 * 128 + x0)) * 32 + f];
        float v11 = a4[((size_t)(y1 * 128 + x1)) * 32 + f];
        float vv = (1.f - fy) * ((1.f - fx) * v00 + fx * v01)
                 + fy * ((1.f - fx) * v10 + fx * v11);
        cat[(size_t)p * 96 + 32 + f] = f2bf(vv);
    }
    {
        float sy = fminf(fmaxf((y + 0.5f) * (1.f / 16.f) - 0.5f, 0.f), 15.f);
        float sx = fminf(fmaxf((x + 0.5f) * (1.f / 16.f) - 0.5f, 0.f), 15.f);
        int y0 = (int)sy; float fy = sy - (float)y0; int y1 = min(y0 + 1, 15);
        int x0 = (int)sx; float fx = sx - (float)x0; int x1 = min(x0 + 1, 15);
        float v00 = a32[((size_t)(y0 * 16 + x0)) * 32 + f];
        float v01 = a32[((size_t)(y0 * 16 + x1)) * 32 + f];
        float v10 = a32[((size_t)(y1 * 16 + x0)) * 32 + f];
        float v11 = a32[((size_t)(y1 * 16 + x1)) * 32 + f];
        float vv = (1.f - fy) * ((1.f - fx) * v00 + fx * v01)
                 + fy * ((1.f - fx) * v10 + fx * v11);
        cat[(size_t)p * 96 + 64 + f] = f2bf(vv);
    }
}

// ---------- 3x3 conv (MFMA) + BN + ReLU -> feat (LDS) -> G = feat @ W0f ----------
__global__ __launch_bounds__(256, 4) void k_fuseG(
    const unsigned short* __restrict__ catb, const short* __restrict__ wfp,
    const float* __restrict__ sf, const float* __restrict__ bfb,
    const short* __restrict__ w0fp, unsigned short* __restrict__ G) {
    __shared__ char Xb[100 * 256];
    int t = threadIdx.x;
    int by = (blockIdx.x >> 5) * 8;
    int bx = (blockIdx.x & 31) * 8;

    if (t < 200) {
        int rp = t >> 1, hf = t & 1;
        int gy = by + rp / 10 - 1;
        int gx = bx + rp % 10 - 1;
        bool ok = (gy >= 0 && gy < 256 && gx >= 0 && gx < 256);
        const unsigned short* src = catb + (size_t)(gy * 256 + gx) * 96 + hf * 48;
        int swz = (rp & 7) << 4;
#pragma unroll
        for (int m = 0; m < 6; ++m) {
            short8v v = {0, 0, 0, 0, 0, 0, 0, 0};
            if (ok) v = *(const short8v*)(src + m * 8);
            *(short8v*)(Xb + rp * 256 + (((hf * 6 + m) * 16) ^ swz)) = v;
        }
    }
    __syncthreads();

    int lane = t & 63, wid = t >> 6;
    int wr = wid >> 1, wc = wid & 1;
    int l15 = lane & 15, g = lane >> 4, kb = g * 16;

    float4v acc[2][3];
#pragma unroll
    for (int rb = 0; rb < 2; ++rb)
#pragma unroll
        for (int n = 0; n < 3; ++n)
            acc[rb][n] = (float4v){0.f, 0.f, 0.f, 0.f};

#pragma unroll
    for (int ky = 0; ky < 3; ++ky) {
#pragma unroll
        for (int kx = 0; kx < 3; ++kx) {
#pragma unroll
            for (int kt = 0; kt < 3; ++kt) {
                const short8v* bp = (const short8v*)wfp
                    + (size_t)((((ky * 3 + kx) * 3 + kt) * 6) + wc * 3) * 64 + lane;
                short8v b0 = bp[0], b1 = bp[64], b2 = bp[128];
#pragma unroll
                for (int rb = 0; rb < 2; ++rb) {
                    int R = wr * 32 + rb * 16 + l15;
                    int rp = ((R >> 3) + ky) * 10 + (R & 7) + kx;
                    short8v a = *(short8v*)(Xb + rp * 256
                                 + ((kt * 64 + kb) ^ ((rp & 7) << 4)));
                    acc[rb][0] = __builtin_amdgcn_mfma_f32_16x16x32_bf16(a, b0, acc[rb][0], 0, 0, 0);
                    acc[rb][1] = __builtin_amdgcn_mfma_f32_16x16x32_bf16(a, b1, acc[rb][1], 0, 0, 0);
                    acc[rb][2] = __builtin_amdgcn_mfma_f32_16x16x32_bf16(a, b2, acc[rb][2], 0, 0, 0);
                }
            }
        }
    }
    __syncthreads();   // conv LDS reads done; Xb reusable

    // feat (bf16, BN+ReLU applied) -> Xb as [64 rows][96 ch], pitch 256, swizzled
#pragma unroll
    for (int rb = 0; rb < 2; ++rb) {
#pragma unroll
        for (int n = 0; n < 3; ++n) {
            int ch = (wc * 3 + n) * 16 + l15;
            float sc = sf[ch], bi = bfb[ch];
#pragma unroll
            for (int j = 0; j < 4; ++j) {
                int R = wr * 32 + rb * 16 + g * 4 + j;
                *(short*)(Xb + R * 256 + ((ch * 2) ^ ((R & 7) << 4))) =
                    (short)f2bf(fmaxf(fmaf(acc[rb][n][j], sc, bi), 0.f));
            }
        }
    }
    __syncthreads();

    // G-stage: 64 rows x 128 cols, K=96. Wave wid owns cols [32*wid, 32*wid+32).
    float4v a2[4][2];
#pragma unroll
    for (int r = 0; r < 4; ++r)
#pragma unroll
        for (int n = 0; n < 2; ++n)
            a2[r][n] = (float4v){0.f, 0.f, 0.f, 0.f};

#pragma unroll
    for (int kt = 0; kt < 3; ++kt) {
        const short8v* bp = (const short8v*)w0fp + (kt * 8 + wid * 2) * 64 + lane;
        short8v b0 = bp[0], b1 = bp[64];
#pragma unroll
        for (int r = 0; r < 4; ++r) {
            int row = r * 16 + l15;
            short8v a = *(short8v*)(Xb + row * 256 + ((kt * 64 + kb) ^ ((row & 7) << 4)));
            a2[r][0] = __builtin_amdgcn_mfma_f32_16x16x32_bf16(a, b0, a2[r][0], 0, 0, 0);
            a2[r][1] = __builtin_amdgcn_mfma_f32_16x16x32_bf16(a, b1, a2[r][1], 0, 0, 0);
        }
    }

#pragma unroll
    for (int r = 0; r < 4; ++r) {
#pragma unroll
        for (int n = 0; n < 2; ++n) {
            int colg = (wid * 2 + n) * 16 + l15;
#pragma unroll
            for (int j = 0; j < 4; ++j) {
                int R = r * 16 + g * 4 + j;
                int pix = (by + (R >> 3)) * 256 + bx + (R & 7);
                G[(size_t)pix * 128 + colg] = f2bf(a2[r][n][j]);
            }
        }
    }
}

// ---------- per-cell MLP: dense GEMM over (cell, case) ----------
// 2048 blocks x 512 thr (8 waves). Wave handles 4 cells (2 pairs sharing B).
// A-tile rows = the 16 cases of ONE cell: A[case][k] = relu(G[cell][k]+corr[case][k]).
// G read is wave-uniform (broadcast); corr pre-swizzled to lane order in LDS.
// pred[cell*16+case] = layer2 dot (pre-bias); ensemble in k_ens.
__global__ __launch_bounds__(512) void k_mlpC(
    const unsigned short* __restrict__ G,
    const float* __restrict__ corr,
    const short* __restrict__ w1p, const float* __restrict__ b1g,
    const float* __restrict__ w2g,
    float* __restrict__ pred) {
    __shared__ short8v Bs[2048];          // 32KB packed W1
    __shared__ float cT[2][4][64][4];     // corrT: [half][kt][lane][j] (8KB)
    __shared__ float b1s[128], w2s[128];
    int t = threadIdx.x;
    int lane = t & 63, wid = t >> 6;      // wid 0..7
    int l15 = lane & 15, g = lane >> 4;

    {
        const short8v* wp = (const short8v*)w1p;
#pragma unroll
        for (int i = 0; i < 4; ++i)
            Bs[t + i * 512] = wp[t + i * 512];
        // corrT[h][kt][ln][j] = corr[(ln&15)*128 + kt*32 + (ln>>4)*8 + h*4 + j]
#pragma unroll
        for (int r = 0; r < 4; ++r) {
            int idx = t + r * 512;                    // 0..2047
            int j = idx & 3, ln = (idx >> 2) & 63;
            int kt = (idx >> 8) & 3, h = idx >> 10;
            cT[h][kt][ln][j] =
                corr[(ln & 15) * 128 + kt * 32 + ((ln >> 4) << 3) + h * 4 + j];
        }
        if (t < 128) b1s[t] = b1g[t];
        else if (t < 256) w2s[t - 128] = w2g[t - 128];
    }
    __syncthreads();

    // XCD-chunked: 8 XCDs x 256 blocks x (8 waves x 4 cells)
    int cell0 = (blockIdx.x & 7) * 8192 + (blockIdx.x >> 3) * 32 + wid * 4;

#pragma unroll
    for (int s = 0; s < 2; ++s) {
        int ca = cell0 + s * 2, cb = ca + 1;
        const unsigned short* gA = G + (size_t)ca * 128 + g * 8;
        const unsigned short* gB = G + (size_t)cb * 128 + g * 8;

        // build A-frags for both cells: relu(G + corr) packed bf16
        short8v afA[4], afB[4];
#pragma unroll
        for (int kt = 0; kt < 4; ++kt) {
            short8v gva = *(const short8v*)(gA + kt * 32);
            short8v gvb = *(const short8v*)(gB + kt * 32);
            float4 c0 = *(const float4*)&cT[0][kt][lane][0];
            float4 c1 = *(const float4*)&cT[1][kt][lane][0];
            uint4v ua, ub;
            ua[0] = cvt_pk_bf16(fmaxf(bf2f((unsigned short)gva[0]) + c0.x, 0.f),
                                fmaxf(bf2f((unsigned short)gva[1]) + c0.y, 0.f));
            ua[1] = cvt_pk_bf16(fmaxf(bf2f((unsigned short)gva[2]) + c0.z, 0.f),
                                fmaxf(bf2f((unsigned short)gva[3]) + c0.w, 0.f));
            ua[2] = cvt_pk_bf16(fmaxf(bf2f((unsigned short)gva[4]) + c1.x, 0.f),
                                fmaxf(bf2f((unsigned short)gva[5]) + c1.y, 0.f));
            ua[3] = cvt_pk_bf16(fmaxf(bf2f((unsigned short)gva[6]) + c1.z, 0.f),
                                fmaxf(bf2f((unsigned short)gva[7]) + c1.w, 0.f));
            ub[0] = cvt_pk_bf16(fmaxf(bf2f((unsigned short)gvb[0]) + c0.x, 0.f),
                                fmaxf(bf2f((unsigned short)gvb[1]) + c0.y, 0.f));
            ub[1] = cvt_pk_bf16(fmaxf(bf2f((unsigned short)gvb[2]) + c0.z, 0.f),
                                fmaxf(bf2f((unsigned short)gvb[3]) + c0.w, 0.f));
            ub[2] = cvt_pk_bf16(fmaxf(bf2f((unsigned short)gvb[4]) + c1.x, 0.f),
                                fmaxf(bf2f((unsigned short)gvb[5]) + c1.y, 0.f));
            ub[3] = cvt_pk_bf16(fmaxf(bf2f((unsigned short)gvb[6]) + c1.z, 0.f),
                                fmaxf(bf2f((unsigned short)gvb[7]) + c1.w, 0.f));
            afA[kt] = __builtin_bit_cast(short8v, ua);
            afB[kt] = __builtin_bit_cast(short8v, ub);
        }

        // layer 1 MFMA (b1 in C-init, nh-halved) + fused layer 2
        float part[2][4];
#pragma unroll
        for (int c = 0; c < 2; ++c)
#pragma unroll
            for (int j = 0; j < 4; ++j) part[c][j] = 0.f;

#pragma unroll
        for (int nh = 0; nh < 2; ++nh) {
            float4v accA[4], accB[4];
            float wv[4];
#pragma unroll
            for (int n = 0; n < 4; ++n) {
                int colg = (nh * 4 + n) * 16 + l15;
                float bv = b1s[colg];
                wv[n] = w2s[colg];
                accA[n] = (float4v){bv, bv, bv, bv};
                accB[n] = (float4v){bv, bv, bv, bv};
            }
            __builtin_amdgcn_s_setprio(1);
#pragma unroll
            for (int kt = 0; kt < 4; ++kt) {
#pragma unroll
                for (int n = 0; n < 4; ++n) {
                    short8v b = Bs[(kt * 8 + nh * 4 + n) * 64 + lane];
                    accA[n] = __builtin_amdgcn_mfma_f32_16x16x32_bf16(afA[kt], b, accA[n], 0, 0, 0);
                    accB[n] = __builtin_amdgcn_mfma_f32_16x16x32_bf16(afB[kt], b, accB[n], 0, 0, 0);
                }
            }
            __builtin_amdgcn_s_setprio(0);
#pragma unroll
            for (int n = 0; n < 4; ++n)
#pragma unroll
                for (int j = 0; j < 4; ++j) {
                    part[0][j] += fmaxf(accA[n][j], 0.f) * wv[n];
                    part[1][j] += fmaxf(accB[n][j], 0.f) * wv[n];
                }
        }

        // reduce over cols (l15) -> row sums; D row = g*4 + j = case
#pragma unroll
        for (int c = 0; c < 2; ++c)
#pragma unroll
            for (int j = 0; j < 4; ++j)
                part[c][j] = dpp_red16(part[c][j]);

        if (l15 == 0) {
            float4 pa = make_float4(part[0][0], part[0][1], part[0][2], part[0][3]);
            float4 pb = make_float4(part[1][0], part[1][1], part[1][2], part[1][3]);
            *(float4*)(pred + (size_t)ca * 16 + g * 4) = pa;
            *(float4*)(pred + (size_t)cb * 16 + g * 4) = pb;
        }
    }
}

// ---------- ensemble pass: per pixel gather 4 preds + areas + combine ----------
__global__ __launch_bounds__(256) void k_ens(
    const float* __restrict__ pred, const float* __restrict__ b2g,
    float* __restrict__ out) {
    int p = blockIdx.x * 256 + threadIdx.x;   // 0..262143
    int qy = p >> 9, qx = p & 511;
    float bb = b2g[0];
    float pr[4], ar[4];
#pragma unroll
    for (int br = 0; br < 4; ++br) {
        int iy = min(max((qy + ((br & 2) ? 1 : -1)) >> 1, 0), 255);
        int ix = min(max((qx + ((br & 1) ? 1 : -1)) >> 1, 0), 255);
        int cy = qy - 2 * iy + 1, cx = qx - 2 * ix + 1;
        pr[br] = pred[((size_t)(iy * 256 + ix) * 16) + cy * 4 + cx] + bb;
        float ry = (float)(qy - 2 * iy) - 0.5f;
        float rx = (float)(qx - 2 * ix) - 0.5f;
        ar[br] = fabsf(ry * rx) + 1e-9f;
    }
    out[p] = (pr[0] * ar[3] + pr[1] * ar[2] + pr[2] * ar[1] + pr[3] * ar[0])
           / (ar[0] + ar[1] + ar[2] + ar[3]);
}

// ---------- host launcher ----------
extern "C" void kernel_launch(void* const* d_in, const int* in_sizes, int n_in,
                              void* d_out, int out_size, void* d_ws, size_t ws_size,
                              hipStream_t stream) {
    const float* feats2 = (const float*)d_in[0];
    const float* feats4 = (const float*)d_in[1];
    const float* feats32 = (const float*)d_in[2];
    const float* w2 = (const float*)d_in[4];
    const float* s2 = (const float*)d_in[5];
    const float* b2 = (const float*)d_in[6];
    const float* w4 = (const float*)d_in[7];
    const float* s4 = (const float*)d_in[8];
    const float* b4 = (const float*)d_in[9];
    const float* w32 = (const float*)d_in[10];
    const float* s32 = (const float*)d_in[11];
    const float* b32 = (const float*)d_in[12];
    const float* wf = (const float*)d_in[13];
    const float* sf = (const float*)d_in[14];
    const float* bf = (const float*)d_in[15];
    const float* mw0 = (const float*)d_in[16];
    const float* mb0 = (const float*)d_in[17];
    const float* mw1 = (const float*)d_in[18];
    const float* mb1 = (const float*)d_in[19];
    const float* mw2 = (const float*)d_in[20];
    const float* mb2 = (const float*)d_in[21];

    float* a4buf = (float*)d_ws;                          // 128*128*32 f32
    float* a32buf = a4buf + 524288;                       // 16*16*32 f32
    unsigned short* catb16 = (unsigned short*)(a32buf + 8192);   // 65536*96 bf16
    unsigned short* Gbuf = catb16 + 6291456;                     // 65536*128 bf16
    short* w1p = (short*)(Gbuf + 8388608);                // 16384 bf16
    short* w0fp = w1p + 16384;                            // 12288 bf16
    short* wfp = w0fp + 12288;                            // 82944 bf16
    float* corrbuf = (float*)(wfp + 82944);               // 16*128 f32
    float* predbuf = corrbuf + 2048;                      // 65536*16 f32 (4MB)

    k_prep<<<2524, 256, 0, stream>>>(mw0, mw1, wf, mb0,
                                     feats4, w4, s4, b4,
                                     feats32, w32, s32, b32,
                                     w1p, w0fp, wfp, corrbuf, a4buf, a32buf);
    k_cat<<<8192, 256, 0, stream>>>(feats2, w2, s2, b2, a4buf, a32buf, catb16);
    k_fuseG<<<1024, 256, 0, stream>>>(catb16, wfp, sf, bf, w0fp, Gbuf);
    k_mlpC<<<2048, 512, 0, stream>>>(Gbuf, corrbuf, w1p, mb1, mw2, predbuf);
    k_ens<<<1024, 256, 0, stream>>>(predbuf, mb2, (float*)d_out);
}

// Round 14
// 133.859 us; speedup vs baseline: 1.6045x; 1.0053x over previous
//
#include <hip/hip_runtime.h>
#include <hip/hip_bf16.h>

typedef __attribute__((ext_vector_type(8))) short short8v;
typedef __attribute__((ext_vector_type(4))) float float4v;
typedef __attribute__((ext_vector_type(4))) unsigned uint4v;

__device__ __forceinline__ unsigned short f2bf(float x) {
    unsigned u = __float_as_uint(x);
    unsigned r = (u + 0x7fffu + ((u >> 16) & 1u)) >> 16;
    return (unsigned short)r;
}
__device__ __forceinline__ float bf2f(unsigned short u) {
    return __uint_as_float((unsigned)u << 16);
}
__device__ __forceinline__ unsigned cvt_pk_bf16(float lo, float hi) {
    unsigned r;
    asm("v_cvt_pk_bf16_f32 %0, %1, %2" : "=v"(r) : "v"(lo), "v"(hi));
    return r;
}
// packed relu on 2 bf16 in a dword: bf16-as-int16 max with 0 == relu (non-NaN)
__device__ __forceinline__ unsigned pk_relu_bf16(unsigned x) {
    unsigned r;
    asm("v_pk_max_i16 %0, %1, %2" : "=v"(r) : "v"(x), "v"(0u));
    return r;
}
// sum across each 16-lane row, result in all lanes (VALU-pipe DPP tree).
__device__ __forceinline__ float dpp_red16(float v) {
    int x = __float_as_int(v);
    v += __int_as_float(__builtin_amdgcn_update_dpp(0, x, 0xB1, 0xF, 0xF, false));
    x = __float_as_int(v);
    v += __int_as_float(__builtin_amdgcn_update_dpp(0, x, 0x4E, 0xF, 0xF, false));
    x = __float_as_int(v);
    v += __int_as_float(__builtin_amdgcn_update_dpp(0, x, 0x124, 0xF, 0xF, false));
    x = __float_as_int(v);
    v += __int_as_float(__builtin_amdgcn_update_dpp(0, x, 0x128, 0xF, 0xF, false));
    return v;
}

// ---------- fused prep: pack2 | packf | corr | branch128 | branch256 ----------
__global__ __launch_bounds__(256) void k_prep(
    const float* __restrict__ mw0, const float* __restrict__ mw1,
    const float* __restrict__ wf, const float* __restrict__ mb0,
    const float* __restrict__ feats4, const float* __restrict__ w4,
    const float* __restrict__ s4, const float* __restrict__ b4,
    const float* __restrict__ feats32, const float* __restrict__ w32,
    const float* __restrict__ s32, const float* __restrict__ b32,
    short* __restrict__ w1p, short* __restrict__ w0fp,
    short* __restrict__ wfp, float* __restrict__ corr,
    float* __restrict__ a4buf, float* __restrict__ a32buf) {
    int b = blockIdx.x, t = threadIdx.x;
    if (b < 112) {
        int i = b * 256 + t;                  // 0..28671
        if (i < 16384) {
            int j = i & 7, l = (i >> 3) & 63;
            int nt = (i >> 9) & 7, kt = i >> 12;
            int k = kt * 32 + ((l >> 4) << 3) + j;
            int n = nt * 16 + (l & 15);
            w1p[i] = (short)f2bf(mw1[k * 128 + n]);
        } else {
            int i2 = i - 16384;               // 0..12287
            int j = i2 & 7, l = (i2 >> 3) & 63;
            int nt = (i2 >> 9) & 7, kt = i2 >> 12;
            int k = kt * 32 + ((l >> 4) << 3) + j;
            int n = nt * 16 + (l & 15);
            w0fp[i2] = (short)f2bf(mw0[k * 128 + n]);
        }
    } else if (b < 436) {
        int i = (b - 112) * 256 + t;          // 0..82943
        if (i < 82944) {
            int j = i & 7, l = (i >> 3) & 63;
            int rest = i >> 9;
            int nt = rest % 6, tk = rest / 6;
            int kt = tk % 3, tap = tk / 3;
            int k = kt * 32 + ((l >> 4) << 3) + j;
            int n = nt * 16 + (l & 15);
            wfp[i] = (short)f2bf(wf[((size_t)(tap * 96 + k)) * 96 + n]);
        }
    } else if (b < 444) {
        int i = (b - 436) * 256 + t;          // 0..2047
        int d = i & 127, c = i >> 7;
        float ry = (float)(c >> 2) - 1.5f;
        float rx = (float)(c & 3) - 1.5f;
        corr[i] = fmaf(ry, mw0[96 * 128 + d], fmaf(rx, mw0[97 * 128 + d], mb0[d]));
    } else if (b < 2492) {
        int f = t & 31;
        int pi = (b - 444) * 8 + (t >> 5);    // 0..16383
        const float* xr = feats4 + (size_t)pi * 128;
        float acc = 0.f;
#pragma unroll 4
        for (int c = 0; c < 128; ++c) acc = fmaf(xr[c], w4[c * 32 + f], acc);
        float v = fmaf(acc, s4[f], b4[f]);
        a4buf[(size_t)pi * 32 + f] = fmaxf(v, 0.f);
    } else {
        int f = t & 31;
        int pi = (b - 2492) * 8 + (t >> 5);   // 0..255
        const float* xr = feats32 + (size_t)pi * 256;
        float acc = 0.f;
#pragma unroll 4
        for (int c = 0; c < 256; ++c) acc = fmaf(xr[c], w32[c * 32 + f], acc);
        float v = fmaf(acc, s32[f], b32[f]);
        a32buf[(size_t)pi * 32 + f] = fmaxf(v, 0.f);
    }
}

// ---------- cat builder: a2 (1x1 conv) + bilinear up of a4, a32 -> bf16 ----------
__global__ __launch_bounds__(256) void k_cat(
    const float* __restrict__ feats2, const float* __restrict__ w2,
    const float* __restrict__ s2, const float* __restrict__ b2,
    const float* __restrict__ a4, const float* __restrict__ a32,
    unsigned short* __restrict__ cat) {
    int t = threadIdx.x;
    int f = t & 31;
    int p = blockIdx.x * 8 + (t >> 5);   // 0..65535
    int y = p >> 8, x = p & 255;

    {
        const float* xr = feats2 + (size_t)p * 64;
        float acc = 0.f;
#pragma unroll 4
        for (int c = 0; c < 64; ++c) acc = fmaf(xr[c], w2[c * 32 + f], acc);
        float v = fmaf(acc, s2[f], b2[f]);
        cat[(size_t)p * 96 + f] = f2bf(fmaxf(v, 0.f));
    }
    {
        float sy = fminf(fmaxf(y * 0.5f - 0.25f, 0.f), 127.f);
        float sx = fminf(fmaxf(x * 0.5f - 0.25f, 0.f), 127.f);
        int y0 = (int)sy; float fy = sy - (float)y0; int y1 = min(y0 + 1, 127);
        int x0 = (int)sx; float fx = sx - (float)x0; int x1 = min(x0 + 1, 127);
        float v00 = a4[((size_t)(y0 * 128 + x0)) * 32 + f];
        float v01 = a4[((size_t)(y0 * 128 + x1)) * 32 + f];
        float v10 = a4[((size_t)(y1 * 128 + x0)) * 32 + f];
        float v11 = a4[((size_t)(y1 * 128 + x1)) * 32 + f];
        float vv = (1.f - fy) * ((1.f - fx) * v00 + fx * v01)
                 + fy * ((1.f - fx) * v10 + fx * v11);
        cat[(size_t)p * 96 + 32 + f] = f2bf(vv);
    }
    {
        float sy = fminf(fmaxf((y + 0.5f) * (1.f / 16.f) - 0.5f, 0.f), 15.f);
        float sx = fminf(fmaxf((x + 0.5f) * (1.f / 16.f) - 0.5f, 0.f), 15.f);
        int y0 = (int)sy; float fy = sy - (float)y0; int y1 = min(y0 + 1, 15);
        int x0 = (int)sx; float fx = sx - (float)x0; int x1 = min(x0 + 1, 15);
        float v00 = a32[((size_t)(y0 * 16 + x0)) * 32 + f];
        float v01 = a32[((size_t)(y0 * 16 + x1)) * 32 + f];
        float v10 = a32[((size_t)(y1 * 16 + x0)) * 32 + f];
        float v11 = a32[((size_t)(y1 * 16 + x1)) * 32 + f];
        float vv = (1.f - fy) * ((1.f - fx) * v00 + fx * v01)
                 + fy * ((1.f - fx) * v10 + fx * v11);
        cat[(size_t)p * 96 + 64 + f] = f2bf(vv);
    }
}

// ---------- 3x3 conv (MFMA) + BN + ReLU -> feat (LDS) -> G = feat @ W0f ----------
__global__ __launch_bounds__(256, 4) void k_fuseG(
    const unsigned short* __restrict__ catb, const short* __restrict__ wfp,
    const float* __restrict__ sf, const float* __restrict__ bfb,
    const short* __restrict__ w0fp, unsigned short* __restrict__ G) {
    __shared__ char Xb[100 * 256];
    int t = threadIdx.x;
    int by = (blockIdx.x >> 5) * 8;
    int bx = (blockIdx.x & 31) * 8;

    if (t < 200) {
        int rp = t >> 1, hf = t & 1;
        int gy = by + rp / 10 - 1;
        int gx = bx + rp % 10 - 1;
        bool ok = (gy >= 0 && gy < 256 && gx >= 0 && gx < 256);
        const unsigned short* src = catb + (size_t)(gy * 256 + gx) * 96 + hf * 48;
        int swz = (rp & 7) << 4;
#pragma unroll
        for (int m = 0; m < 6; ++m) {
            short8v v = {0, 0, 0, 0, 0, 0, 0, 0};
            if (ok) v = *(const short8v*)(src + m * 8);
            *(short8v*)(Xb + rp * 256 + (((hf * 6 + m) * 16) ^ swz)) = v;
        }
    }
    __syncthreads();

    int lane = t & 63, wid = t >> 6;
    int wr = wid >> 1, wc = wid & 1;
    int l15 = lane & 15, g = lane >> 4, kb = g * 16;

    float4v acc[2][3];
#pragma unroll
    for (int rb = 0; rb < 2; ++rb)
#pragma unroll
        for (int n = 0; n < 3; ++n)
            acc[rb][n] = (float4v){0.f, 0.f, 0.f, 0.f};

#pragma unroll
    for (int ky = 0; ky < 3; ++ky) {
#pragma unroll
        for (int kx = 0; kx < 3; ++kx) {
#pragma unroll
            for (int kt = 0; kt < 3; ++kt) {
                const short8v* bp = (const short8v*)wfp
                    + (size_t)((((ky * 3 + kx) * 3 + kt) * 6) + wc * 3) * 64 + lane;
                short8v b0 = bp[0], b1 = bp[64], b2 = bp[128];
#pragma unroll
                for (int rb = 0; rb < 2; ++rb) {
                    int R = wr * 32 + rb * 16 + l15;
                    int rp = ((R >> 3) + ky) * 10 + (R & 7) + kx;
                    short8v a = *(short8v*)(Xb + rp * 256
                                 + ((kt * 64 + kb) ^ ((rp & 7) << 4)));
                    acc[rb][0] = __builtin_amdgcn_mfma_f32_16x16x32_bf16(a, b0, acc[rb][0], 0, 0, 0);
                    acc[rb][1] = __builtin_amdgcn_mfma_f32_16x16x32_bf16(a, b1, acc[rb][1], 0, 0, 0);
                    acc[rb][2] = __builtin_amdgcn_mfma_f32_16x16x32_bf16(a, b2, acc[rb][2], 0, 0, 0);
                }
            }
        }
    }
    __syncthreads();   // conv LDS reads done; Xb reusable

    // feat (bf16, BN+ReLU applied) -> Xb as [64 rows][96 ch], pitch 256, swizzled
#pragma unroll
    for (int rb = 0; rb < 2; ++rb) {
#pragma unroll
        for (int n = 0; n < 3; ++n) {
            int ch = (wc * 3 + n) * 16 + l15;
            float sc = sf[ch], bi = bfb[ch];
#pragma unroll
            for (int j = 0; j < 4; ++j) {
                int R = wr * 32 + rb * 16 + g * 4 + j;
                *(short*)(Xb + R * 256 + ((ch * 2) ^ ((R & 7) << 4))) =
                    (short)f2bf(fmaxf(fmaf(acc[rb][n][j], sc, bi), 0.f));
            }
        }
    }
    __syncthreads();

    // G-stage: 64 rows x 128 cols, K=96. Wave wid owns cols [32*wid, 32*wid+32).
    float4v a2[4][2];
#pragma unroll
    for (int r = 0; r < 4; ++r)
#pragma unroll
        for (int n = 0; n < 2; ++n)
            a2[r][n] = (float4v){0.f, 0.f, 0.f, 0.f};

#pragma unroll
    for (int kt = 0; kt < 3; ++kt) {
        const short8v* bp = (const short8v*)w0fp + (kt * 8 + wid * 2) * 64 + lane;
        short8v b0 = bp[0], b1 = bp[64];
#pragma unroll
        for (int r = 0; r < 4; ++r) {
            int row = r * 16 + l15;
            short8v a = *(short8v*)(Xb + row * 256 + ((kt * 64 + kb) ^ ((row & 7) << 4)));
            a2[r][0] = __builtin_amdgcn_mfma_f32_16x16x32_bf16(a, b0, a2[r][0], 0, 0, 0);
            a2[r][1] = __builtin_amdgcn_mfma_f32_16x16x32_bf16(a, b1, a2[r][1], 0, 0, 0);
        }
    }

#pragma unroll
    for (int r = 0; r < 4; ++r) {
#pragma unroll
        for (int n = 0; n < 2; ++n) {
            int colg = (wid * 2 + n) * 16 + l15;
#pragma unroll
            for (int j = 0; j < 4; ++j) {
                int R = r * 16 + g * 4 + j;
                int pix = (by + (R >> 3)) * 256 + bx + (R & 7);
                G[(size_t)pix * 128 + colg] = f2bf(a2[r][n][j]);
            }
        }
    }
}

// ---------- per-cell MLP: dense GEMM over (cell, case), u32-packed A-build ----------
// A[case][k] = relu(G[cell][k] + corr[case][k]); per u32 (2 bf16): shl/and
// unpack + 2 f32 adds + cvt_pk + v_pk_max_i16 (packed relu) = 6 VALU / 2 elems.
__global__ __launch_bounds__(512) void k_mlpC(
    const unsigned short* __restrict__ G,
    const float* __restrict__ corr,
    const short* __restrict__ w1p, const float* __restrict__ b1g,
    const float* __restrict__ w2g,
    float* __restrict__ pred) {
    __shared__ short8v Bs[2048];          // 32KB packed W1
    __shared__ float cT[2][4][64][4];     // corrT: [half][kt][lane][j] (8KB)
    __shared__ float b1s[128], w2s[128];
    int t = threadIdx.x;
    int lane = t & 63, wid = t >> 6;      // wid 0..7
    int l15 = lane & 15, g = lane >> 4;

    {
        const short8v* wp = (const short8v*)w1p;
#pragma unroll
        for (int i = 0; i < 4; ++i)
            Bs[t + i * 512] = wp[t + i * 512];
        // cT[h][kt][ln][j] = corr[(ln&15)*128 + kt*32 + (ln>>4)*8 + h*4 + j]
#pragma unroll
        for (int r = 0; r < 4; ++r) {
            int idx = t + r * 512;                    // 0..2047
            int j = idx & 3, ln = (idx >> 2) & 63;
            int kt = (idx >> 8) & 3, h = idx >> 10;
            cT[h][kt][ln][j] =
                corr[(ln & 15) * 128 + kt * 32 + ((ln >> 4) << 3) + h * 4 + j];
        }
        if (t < 128) b1s[t] = b1g[t];
        else if (t < 256) w2s[t - 128] = w2g[t - 128];
    }
    __syncthreads();

    // XCD-chunked: 8 XCDs x 256 blocks x (8 waves x 4 cells)
    int cell0 = (blockIdx.x & 7) * 8192 + (blockIdx.x >> 3) * 32 + wid * 4;
    // G as u32 units: row = 64 u32; this lane's slice = g*4 u32; kt step = 16 u32
    const unsigned* gbase = (const unsigned*)G + (size_t)cell0 * 64 + g * 4;

#pragma unroll
    for (int s = 0; s < 2; ++s) {
        const unsigned* gA = gbase + s * 128;       // cell ca
        const unsigned* gB = gA + 64;               // cell cb

        // build A-frags for both cells (u32-packed pipeline)
        short8v afA[4], afB[4];
#pragma unroll
        for (int kt = 0; kt < 4; ++kt) {
            uint4v wa = *(const uint4v*)(gA + kt * 16);
            uint4v wb = *(const uint4v*)(gB + kt * 16);
            float4 c0 = *(const float4*)&cT[0][kt][lane][0];
            float4 c1 = *(const float4*)&cT[1][kt][lane][0];
            uint4v ua, ub;
            {
                unsigned w = wa[0];
                ua[0] = pk_relu_bf16(cvt_pk_bf16(
                    __uint_as_float(w << 16) + c0.x,
                    __uint_as_float(w & 0xFFFF0000u) + c0.y));
                w = wa[1];
                ua[1] = pk_relu_bf16(cvt_pk_bf16(
                    __uint_as_float(w << 16) + c0.z,
                    __uint_as_float(w & 0xFFFF0000u) + c0.w));
                w = wa[2];
                ua[2] = pk_relu_bf16(cvt_pk_bf16(
                    __uint_as_float(w << 16) + c1.x,
                    __uint_as_float(w & 0xFFFF0000u) + c1.y));
                w = wa[3];
                ua[3] = pk_relu_bf16(cvt_pk_bf16(
                    __uint_as_float(w << 16) + c1.z,
                    __uint_as_float(w & 0xFFFF0000u) + c1.w));
            }
            {
                unsigned w = wb[0];
                ub[0] = pk_relu_bf16(cvt_pk_bf16(
                    __uint_as_float(w << 16) + c0.x,
                    __uint_as_float(w & 0xFFFF0000u) + c0.y));
                w = wb[1];
                ub[1] = pk_relu_bf16(cvt_pk_bf16(
                    __uint_as_float(w << 16) + c0.z,
                    __uint_as_float(w & 0xFFFF0000u) + c0.w));
                w = wb[2];
                ub[2] = pk_relu_bf16(cvt_pk_bf16(
                    __uint_as_float(w << 16) + c1.x,
                    __uint_as_float(w & 0xFFFF0000u) + c1.y));
                w = wb[3];
                ub[3] = pk_relu_bf16(cvt_pk_bf16(
                    __uint_as_float(w << 16) + c1.z,
                    __uint_as_float(w & 0xFFFF0000u) + c1.w));
            }
            afA[kt] = __builtin_bit_cast(short8v, ua);
            afB[kt] = __builtin_bit_cast(short8v, ub);
        }

        // layer 1 MFMA (b1 in C-init, nh-halved) + fused layer 2
        float part[2][4];
#pragma unroll
        for (int c = 0; c < 2; ++c)
#pragma unroll
            for (int j = 0; j < 4; ++j) part[c][j] = 0.f;

#pragma unroll
        for (int nh = 0; nh < 2; ++nh) {
            float4v accA[4], accB[4];
            float wv[4];
#pragma unroll
            for (int n = 0; n < 4; ++n) {
                int colg = (nh * 4 + n) * 16 + l15;
                float bv = b1s[colg];
                wv[n] = w2s[colg];
                accA[n] = (float4v){bv, bv, bv, bv};
                accB[n] = (float4v){bv, bv, bv, bv};
            }
            __builtin_amdgcn_s_setprio(1);
#pragma unroll
            for (int kt = 0; kt < 4; ++kt) {
#pragma unroll
                for (int n = 0; n < 4; ++n) {
                    short8v b = Bs[(kt * 8 + nh * 4 + n) * 64 + lane];
                    accA[n] = __builtin_amdgcn_mfma_f32_16x16x32_bf16(afA[kt], b, accA[n], 0, 0, 0);
                    accB[n] = __builtin_amdgcn_mfma_f32_16x16x32_bf16(afB[kt], b, accB[n], 0, 0, 0);
                }
            }
            __builtin_amdgcn_s_setprio(0);
#pragma unroll
            for (int n = 0; n < 4; ++n)
#pragma unroll
                for (int j = 0; j < 4; ++j) {
                    part[0][j] += fmaxf(accA[n][j], 0.f) * wv[n];
                    part[1][j] += fmaxf(accB[n][j], 0.f) * wv[n];
                }
        }

        // reduce over cols (l15) -> row sums; D row = g*4 + j = case
#pragma unroll
        for (int c = 0; c < 2; ++c)
#pragma unroll
            for (int j = 0; j < 4; ++j)
                part[c][j] = dpp_red16(part[c][j]);

        if (l15 == 0) {
            int ca = cell0 + s * 2;
            float4 pa = make_float4(part[0][0], part[0][1], part[0][2], part[0][3]);
            float4 pb = make_float4(part[1][0], part[1][1], part[1][2], part[1][3]);
            *(float4*)(pred + (size_t)ca * 16 + g * 4) = pa;
            *(float4*)(pred + (size_t)(ca + 1) * 16 + g * 4) = pb;
        }
    }
}

// ---------- ensemble pass: per pixel gather 4 preds + areas + combine ----------
__global__ __launch_bounds__(256) void k_ens(
    const float* __restrict__ pred, const float* __restrict__ b2g,
    float* __restrict__ out) {
    int p = blockIdx.x * 256 + threadIdx.x;   // 0..262143
    int qy = p >> 9, qx = p & 511;
    float bb = b2g[0];
    float pr[4], ar[4];
#pragma unroll
    for (int br = 0; br < 4; ++br) {
        int iy = min(max((qy + ((br & 2) ? 1 : -1)) >> 1, 0), 255);
        int ix = min(max((qx + ((br & 1) ? 1 : -1)) >> 1, 0), 255);
        int cy = qy - 2 * iy + 1, cx = qx - 2 * ix + 1;
        pr[br] = pred[((size_t)(iy * 256 + ix) * 16) + cy * 4 + cx] + bb;
        float ry = (float)(qy - 2 * iy) - 0.5f;
        float rx = (float)(qx - 2 * ix) - 0.5f;
        ar[br] = fabsf(ry * rx) + 1e-9f;
    }
    out[p] = (pr[0] * ar[3] + pr[1] * ar[2] + pr[2] * ar[1] + pr[3] * ar[0])
           / (ar[0] + ar[1] + ar[2] + ar[3]);
}

// ---------- host launcher ----------
extern "C" void kernel_launch(void* const* d_in, const int* in_sizes, int n_in,
                              void* d_out, int out_size, void* d_ws, size_t ws_size,
                              hipStream_t stream) {
    const float* feats2 = (const float*)d_in[0];
    const float* feats4 = (const float*)d_in[1];
    const float* feats32 = (const float*)d_in[2];
    const float* w2 = (const float*)d_in[4];
    const float* s2 = (const float*)d_in[5];
    const float* b2 = (const float*)d_in[6];
    const float* w4 = (const float*)d_in[7];
    const float* s4 = (const float*)d_in[8];
    const float* b4 = (const float*)d_in[9];
    const float* w32 = (const float*)d_in[10];
    const float* s32 = (const float*)d_in[11];
    const float* b32 = (const float*)d_in[12];
    const float* wf = (const float*)d_in[13];
    const float* sf = (const float*)d_in[14];
    const float* bf = (const float*)d_in[15];
    const float* mw0 = (const float*)d_in[16];
    const float* mb0 = (const float*)d_in[17];
    const float* mw1 = (const float*)d_in[18];
    const float* mb1 = (const float*)d_in[19];
    const float* mw2 = (const float*)d_in[20];
    const float* mb2 = (const float*)d_in[21];

    float* a4buf = (float*)d_ws;                          // 128*128*32 f32
    float* a32buf = a4buf + 524288;                       // 16*16*32 f32
    unsigned short* catb16 = (unsigned short*)(a32buf + 8192);   // 65536*96 bf16
    unsigned short* Gbuf = catb16 + 6291456;                     // 65536*128 bf16
    short* w1p = (short*)(Gbuf + 8388608);                // 16384 bf16
    short* w0fp = w1p + 16384;                            // 12288 bf16
    short* wfp = w0fp + 12288;                            // 82944 bf16
    float* corrbuf = (float*)(wfp + 82944);               // 16*128 f32
    float* predbuf = corrbuf + 2048;                      // 65536*16 f32 (4MB)

    k_prep<<<2524, 256, 0, stream>>>(mw0, mw1, wf, mb0,
                                     feats4, w4, s4, b4,
                                     feats32, w32, s32, b32,
                                     w1p, w0fp, wfp, corrbuf, a4buf, a32buf);
    k_cat<<<8192, 256, 0, stream>>>(feats2, w2, s2, b2, a4buf, a32buf, catb16);
    k_fuseG<<<1024, 256, 0, stream>>>(catb16, wfp, sf, bf, w0fp, Gbuf);
    k_mlpC<<<2048, 512, 0, stream>>>(Gbuf, corrbuf, w1p, mb1, mw2, predbuf);
    k_ens<<<1024, 256, 0, stream>>>(predbuf, mb2, (float*)d_out);
}